// Round 2
// baseline (1476.213 us; speedup 1.0000x reference)
//
#include <hip/hip_runtime.h>
#include <hip/hip_bf16.h>

// dims
#define BB 4
#define LL 4096
#define DM 1024
#define HH 16
#define DHD 64
#define KB 8
#define BL 16384  // BB*LL

typedef __attribute__((ext_vector_type(8))) short short8;
typedef __attribute__((ext_vector_type(4))) short short4v;
typedef __attribute__((ext_vector_type(4))) float float4v;

#define MFMA16(A, Bx, C) __builtin_amdgcn_mfma_f32_16x16x32_bf16(A, Bx, C, 0, 0, 0)

static __device__ __forceinline__ short bf16s(float f) {
  __hip_bfloat16 h = __float2bfloat16(f);
  return *reinterpret_cast<short*>(&h);
}

// ---------------------------------------------------------------------------
// prep_wt: transpose wq/wk/wv/wo ([k][n] fp32) -> [n][k] bf16
// grid 1024 blocks: s = blk>>8 (0..3), 16x16 tiles of 64x64
// ---------------------------------------------------------------------------
__global__ __launch_bounds__(256) void prep_wt(const float* __restrict__ wq,
                                               const float* __restrict__ wk,
                                               const float* __restrict__ wv,
                                               const float* __restrict__ wo,
                                               __hip_bfloat16* __restrict__ wt_qkv,
                                               __hip_bfloat16* __restrict__ wt_o) {
  int blk = blockIdx.x;
  int s = blk >> 8;
  int rem = blk & 255;
  int k0 = (rem >> 4) * 64;
  int n0 = (rem & 15) * 64;
  const float* src = (s == 0) ? wq : (s == 1) ? wk : (s == 2) ? wv : wo;
  __hip_bfloat16* dst = (s < 3) ? (wt_qkv + (size_t)s * 1024 * 1024) : wt_o;
  __shared__ float ls[64][65];
  int t = threadIdx.x;
#pragma unroll
  for (int p = 0; p < 4; ++p) {
    int sid = p * 256 + t;
    int r = sid >> 4, c4 = sid & 15;
    float4 v = *reinterpret_cast<const float4*>(src + (size_t)(k0 + r) * 1024 + n0 + c4 * 4);
    ls[r][c4 * 4 + 0] = v.x; ls[r][c4 * 4 + 1] = v.y;
    ls[r][c4 * 4 + 2] = v.z; ls[r][c4 * 4 + 3] = v.w;
  }
  __syncthreads();
#pragma unroll
  for (int p = 0; p < 4; ++p) {
    int sid = p * 256 + t;
    int n = sid >> 4, kq = sid & 15;
    short4v pk;
#pragma unroll
    for (int j = 0; j < 4; ++j) pk[j] = bf16s(ls[kq * 4 + j][n]);
    *reinterpret_cast<short4v*>(dst + (size_t)(n0 + n) * 1024 + k0 + kq * 4) = pk;
  }
}

// ---------------------------------------------------------------------------
// prep_wsc: fused score weights  Wsc[col][d] (fp64, col-major) and bias bsc[col]
// col = side*128 + h*8 + kk ; Wsc[col][d] = sum_dh w_side[d][h][dh]*mix[h][dh][kk]
// mix computed in fp64 to track an fp64 reference as closely as possible.
// grid 256 blocks (one col each), 256 threads
// ---------------------------------------------------------------------------
__global__ __launch_bounds__(256) void prep_wsc(const float* __restrict__ wq,
                                                const float* __restrict__ wk,
                                                const float* __restrict__ wsh,
                                                const float* __restrict__ wqs,
                                                const float* __restrict__ wks,
                                                const float* __restrict__ bq,
                                                const float* __restrict__ bk,
                                                double* __restrict__ wsc,
                                                double* __restrict__ bsc) {
  int col = blockIdx.x;
  int side = col >> 7, h = (col >> 3) & 15, kk = col & 7;
  const float* w = side ? wk : wq;
  const float* wscore = side ? wks : wqs;
  __shared__ double mix[64];
  int t = threadIdx.x;
  if (t < 64)
    mix[t] = 0.9 * (double)wsh[(h * 64 + t) * 8 + kk] +
             0.1 * (double)wscore[(h * 64 + t) * 8 + kk];
  __syncthreads();
#pragma unroll
  for (int p = 0; p < 4; ++p) {
    int d = p * 256 + t;
    double acc = 0.0;
    const float* wr = w + (size_t)d * 1024 + h * 64;
#pragma unroll
    for (int j = 0; j < 64; ++j) acc += (double)wr[j] * mix[j];
    wsc[(size_t)col * 1024 + d] = acc;
  }
  if (t == 0) {
    const float* br = (side ? bk : bq) + h * 64;
    double acc = 0.0;
    for (int j = 0; j < 64; ++j) acc += (double)br[j] * mix[j];
    bsc[col] = acc;
  }
}

// ---------------------------------------------------------------------------
// score_kernel: qs/ks in fp64, argmax -> bid, softmax prob sums -> psumg
// 512 threads: lane = token (64/block), wave = col-group of 32
// grid 256 blocks
// ---------------------------------------------------------------------------
__global__ __launch_bounds__(512) void score_kernel(const float* __restrict__ x,
                                                    const double* __restrict__ wsc,
                                                    const double* __restrict__ bsc,
                                                    int* __restrict__ bid,
                                                    float* __restrict__ psumg) {
  __shared__ float sp[256];
  int t = threadIdx.x;
  if (t < 256) sp[t] = 0.f;
  __syncthreads();
  int lane = t & 63;
  int colq = __builtin_amdgcn_readfirstlane(t >> 6);  // 0..7 wave-uniform
  int T0 = blockIdx.x * 64;
  int b = T0 >> 12;
  int l = (T0 + lane) & 4095;  // token index WITHIN the (side,b,h) slab
  const float* xr = x + (size_t)(T0 + lane) * 1024;
  double acc[32];
#pragma unroll
  for (int c = 0; c < 32; ++c) acc[c] = bsc[colq * 32 + c];
  for (int kt = 0; kt < 64; ++kt) {
    int k0 = kt * 16;
    double xd[16];
#pragma unroll
    for (int j = 0; j < 4; ++j) {
      float4 v = *reinterpret_cast<const float4*>(xr + k0 + j * 4);
      xd[j * 4 + 0] = (double)v.x; xd[j * 4 + 1] = (double)v.y;
      xd[j * 4 + 2] = (double)v.z; xd[j * 4 + 3] = (double)v.w;
    }
#pragma unroll
    for (int c = 0; c < 32; ++c) {
      const double* wp = wsc + (size_t)(colq * 32 + c) * 1024 + k0;  // uniform -> s_load
#pragma unroll
      for (int d = 0; d < 16; ++d) acc[c] += xd[d] * wp[d];
    }
  }
#pragma unroll
  for (int g = 0; g < 4; ++g) {
    float v[8];
#pragma unroll
    for (int j = 0; j < 8; ++j) v[j] = (float)acc[g * 8 + j];
    float mx = v[0]; int am = 0;
#pragma unroll
    for (int j = 1; j < 8; ++j) { if (v[j] > mx) { mx = v[j]; am = j; } }  // first-max
    float es = 0.f, e[8];
#pragma unroll
    for (int j = 0; j < 8; ++j) { e[j] = __expf(v[j] - mx); es += e[j]; }
    float inv = 1.f / es;
    int col = colq * 32 + g * 8;
#pragma unroll
    for (int j = 0; j < 8; ++j) atomicAdd(&sp[col + j], e[j] * inv);
    int side = col >> 7, h = (col >> 3) & 15;
    bid[(((side * 4 + b) * 16 + h) << 12) + l] = am;
  }
  __syncthreads();
  if (t < 256) {
    int col = t;
    int side = col >> 7, h = (col >> 3) & 15, kk = col & 7;
    atomicAdd(&psumg[((side * 4 + b) * 16 + h) * 8 + kk], sp[t]);
  }
}

// ---------------------------------------------------------------------------
// sort_kernel: stable counting sort of 4096 tokens into 8 buckets per (side,b,h)
// grid 128 (side,b,h), 256 threads x 16 tokens
// ---------------------------------------------------------------------------
__global__ __launch_bounds__(256) void sort_kernel(const int* __restrict__ bid,
                                                   int* __restrict__ sortq,
                                                   int* __restrict__ sortk,
                                                   int* __restrict__ cntg) {
  int blk = blockIdx.x;
  int side = blk >> 6, b = (blk >> 4) & 3, h = blk & 15;
  const int* ids = bid + (((side * 4 + b) * 16 + h) << 12);
  int* outp = (side ? sortk : sortq) + ((b * 16 + h) << 12);
  __shared__ int cnt[8][257];
  __shared__ int base[8];
  int t = threadIdx.x;
  int loc[16];
  int hist[8] = {0, 0, 0, 0, 0, 0, 0, 0};
#pragma unroll
  for (int j = 0; j < 16; ++j) { loc[j] = ids[t * 16 + j] & 7; hist[loc[j]]++; }
#pragma unroll
  for (int k = 0; k < 8; ++k) cnt[k][t + 1] = hist[k];
  if (t < 8) cnt[t][0] = 0;
  __syncthreads();
  if (t < 8) {
    for (int i = 1; i <= 256; ++i) cnt[t][i] += cnt[t][i - 1];
  }
  __syncthreads();
  if (t == 0) {
    int run = 0;
    for (int k = 0; k < 8; ++k) { base[k] = run; run += cnt[k][256]; }
  }
  if (t < 8) cntg[((side * 4 + b) * 16 + h) * 8 + t] = cnt[t][256];
  __syncthreads();
#pragma unroll
  for (int j = 0; j < 16; ++j) {
    int k = loc[j];
    int before = 0;
#pragma unroll
    for (int i = 0; i < 16; ++i) before += (i < j && loc[i] == k) ? 1 : 0;
    int pos = base[k] + cnt[k][t] + before;
    outp[pos] = t * 16 + j;
  }
}

// ---------------------------------------------------------------------------
// gemm_k: C[M,N] = A[M,1024] * Bt[N,1024]^T (+bias). 128x128 tile, BK=64,
// 16x16x32 bf16 MFMA, swizzled LDS (phys chunk = (kc+row)&7) conflict-free.
// AF32=true: A fp32 (inputs_q), C bf16 into qkv[s]; AF32=false: A bf16, C fp32.
// ---------------------------------------------------------------------------
template <bool AF32>
__global__ __launch_bounds__(256) void gemm_k(const void* __restrict__ Av,
                                              const __hip_bfloat16* __restrict__ Bt,
                                              void* __restrict__ Cv,
                                              const float* __restrict__ b0,
                                              const float* __restrict__ b1,
                                              const float* __restrict__ b2) {
  __shared__ char sm[32768];
  int t = threadIdx.x;
  int m0 = blockIdx.x * 128;
  int n0 = blockIdx.y * 128;
  int lane = t & 63, w = t >> 6;
  int lm = lane & 15, quad = lane >> 4;
  int wm = (w & 1) * 64, wn = (w >> 1) * 64;
  float4v zero = {0.f, 0.f, 0.f, 0.f};
  float4v acc[4][4];
#pragma unroll
  for (int i = 0; i < 4; ++i)
#pragma unroll
    for (int j = 0; j < 4; ++j) acc[i][j] = zero;

  for (int k0 = 0; k0 < 1024; k0 += 64) {
    __syncthreads();
#pragma unroll
    for (int p = 0; p < 4; ++p) {
      int sid = p * 256 + t;
      int m = sid >> 3, kc = sid & 7;
      short8 val;
      if constexpr (AF32) {
        const float* ap = (const float*)Av + (size_t)(m0 + m) * 1024 + k0 + kc * 8;
        float4 f0 = *reinterpret_cast<const float4*>(ap);
        float4 f1 = *reinterpret_cast<const float4*>(ap + 4);
        val[0] = bf16s(f0.x); val[1] = bf16s(f0.y); val[2] = bf16s(f0.z); val[3] = bf16s(f0.w);
        val[4] = bf16s(f1.x); val[5] = bf16s(f1.y); val[6] = bf16s(f1.z); val[7] = bf16s(f1.w);
      } else {
        val = *reinterpret_cast<const short8*>((const __hip_bfloat16*)Av +
                                               (size_t)(m0 + m) * 1024 + k0 + kc * 8);
      }
      *reinterpret_cast<short8*>(sm + m * 128 + ((kc + m) & 7) * 16) = val;
      short8 bvv = *reinterpret_cast<const short8*>(Bt + (size_t)(n0 + m) * 1024 + k0 + kc * 8);
      *reinterpret_cast<short8*>(sm + 16384 + m * 128 + ((kc + m) & 7) * 16) = bvv;
    }
    __syncthreads();
#pragma unroll
    for (int kh = 0; kh < 2; ++kh) {
      short8 af[4], bf[4];
#pragma unroll
      for (int i = 0; i < 4; ++i) {
        int row = wm + i * 16 + lm;
        int ph = ((kh * 4 + quad) + row) & 7;
        af[i] = *reinterpret_cast<const short8*>(sm + row * 128 + ph * 16);
        int rn = wn + i * 16 + lm;
        int phb = ((kh * 4 + quad) + rn) & 7;
        bf[i] = *reinterpret_cast<const short8*>(sm + 16384 + rn * 128 + phb * 16);
      }
#pragma unroll
      for (int i = 0; i < 4; ++i)
#pragma unroll
        for (int j = 0; j < 4; ++j) acc[i][j] = MFMA16(af[i], bf[j], acc[i][j]);
    }
  }

  if constexpr (AF32) {
    int s = n0 >> 10, nnb = n0 & 1023;
    const float* bias = (s == 0) ? b0 : (s == 1) ? b1 : b2;
    __hip_bfloat16* C = (__hip_bfloat16*)Cv + (size_t)s * BL * 1024;
#pragma unroll
    for (int i = 0; i < 4; ++i)
#pragma unroll
      for (int j = 0; j < 4; ++j) {
        int nn = nnb + wn + j * 16 + lm;
        float bvx = bias[nn];
#pragma unroll
        for (int r = 0; r < 4; ++r) {
          int row = m0 + wm + i * 16 + quad * 4 + r;
          C[(size_t)row * 1024 + nn] = __float2bfloat16(acc[i][j][r] + bvx);
        }
      }
  } else {
    float* C = (float*)Cv;
#pragma unroll
    for (int i = 0; i < 4; ++i)
#pragma unroll
      for (int j = 0; j < 4; ++j) {
        int gn = n0 + wn + j * 16 + lm;
        float bvx = b0[gn];
#pragma unroll
        for (int r = 0; r < 4; ++r) {
          int row = m0 + wm + i * 16 + quad * 4 + r;
          C[(size_t)row * 1024 + gn] = acc[i][j][r] + bvx;
        }
      }
  }
}

// ---------------------------------------------------------------------------
// vt_kernel: gather sorted V and transpose -> vT[cid][dim][key] (512 keys/chunk)
// grid 512 chunks, 256 threads
// ---------------------------------------------------------------------------
__global__ __launch_bounds__(256) void vt_kernel(const __hip_bfloat16* __restrict__ vb,
                                                 const int* __restrict__ sortk,
                                                 __hip_bfloat16* __restrict__ vT) {
  int cid = blockIdx.x;
  int b = cid >> 7, h = (cid >> 3) & 15, n = cid & 7;
  int sbase = ((b * 16 + h) << 12) + n * 512;
  __shared__ __hip_bfloat16 ls[64][72];
  int t = threadIdx.x;
  for (int kt = 0; kt < 8; ++kt) {
    __syncthreads();
#pragma unroll
    for (int p = 0; p < 2; ++p) {
      int sid = p * 256 + t;
      int key = sid >> 3, kc = sid & 7;
      int tok = sortk[sbase + kt * 64 + key];
      short8 v = *reinterpret_cast<const short8*>(vb + ((size_t)(b * 4096 + tok) * 16 + h) * 64 + kc * 8);
      *reinterpret_cast<short8*>(&ls[key][kc * 8]) = v;
    }
    __syncthreads();
#pragma unroll
    for (int p = 0; p < 2; ++p) {
      int sid = p * 256 + t;
      int dim = sid >> 3, kc = sid & 7;
      short8 o;
#pragma unroll
      for (int j = 0; j < 8; ++j) o[j] = *reinterpret_cast<short*>(&ls[kc * 8 + j][dim]);
      *reinterpret_cast<short8*>(vT + ((size_t)cid * 64 + dim) * 512 + kt * 64 + kc * 8) = o;
    }
  }
}

// ---------------------------------------------------------------------------
// attn_kernel: per (chunk, 64-query tile). Wave = 16 queries. K-tiles of 64.
// S = Q*K^T (MFMA), exp (no max-sub; logits are tiny), P->LDS, O += P*V (MFMA),
// divide by row-sum, scatter to attn_out[token][h][dh] via sortq.
// grid 4096 blocks, 256 threads
// ---------------------------------------------------------------------------
__global__ __launch_bounds__(256) void attn_kernel(const __hip_bfloat16* __restrict__ qb,
                                                   const __hip_bfloat16* __restrict__ kb,
                                                   const __hip_bfloat16* __restrict__ vT,
                                                   const int* __restrict__ sortq,
                                                   const int* __restrict__ sortk,
                                                   __hip_bfloat16* __restrict__ ao) {
  __shared__ char sm[25600];  // Ks 8K | Vs 8K | Ps 4 waves x 16 x 144B
  int t = threadIdx.x;
  int lane = t & 63, w = t >> 6;
  int lm = lane & 15, quad = lane >> 4;
  int cid = blockIdx.x >> 3, qt = blockIdx.x & 7;
  int b = cid >> 7, h = (cid >> 3) & 15, n = cid & 7;
  int sbase = (b * 16 + h) << 12;
  int psOff = 16384 + w * 2304;

  int qtok = sortq[sbase + n * 512 + qt * 64 + w * 16 + lm];
  const __hip_bfloat16* qp = qb + ((size_t)(b * 4096 + qtok) * 16 + h) * 64 + quad * 8;
  short8 aq0 = *reinterpret_cast<const short8*>(qp);
  short8 aq1 = *reinterpret_cast<const short8*>(qp + 32);

  float4v zero = {0.f, 0.f, 0.f, 0.f};
  float4v accO[4];
#pragma unroll
  for (int i = 0; i < 4; ++i) accO[i] = zero;
  float lsum[4] = {0.f, 0.f, 0.f, 0.f};

  for (int kt = 0; kt < 8; ++kt) {
    __syncthreads();
#pragma unroll
    for (int p = 0; p < 2; ++p) {
      int sid = p * 256 + t;
      int row = sid >> 3, kc = sid & 7;
      int tok = sortk[sbase + n * 512 + kt * 64 + row];
      short8 kv = *reinterpret_cast<const short8*>(kb + ((size_t)(b * 4096 + tok) * 16 + h) * 64 + kc * 8);
      *reinterpret_cast<short8*>(sm + row * 128 + ((kc + row) & 7) * 16) = kv;
      short8 vv = *reinterpret_cast<const short8*>(vT + ((size_t)cid * 64 + row) * 512 + kt * 64 + kc * 8);
      *reinterpret_cast<short8*>(sm + 8192 + row * 128 + ((kc + row) & 7) * 16) = vv;
    }
    __syncthreads();
#pragma unroll
    for (int nt = 0; nt < 4; ++nt) {
      int key = nt * 16 + lm;
      int ph0 = (quad + key) & 7;
      int ph1 = (4 + quad + key) & 7;
      short8 bk0 = *reinterpret_cast<const short8*>(sm + key * 128 + ph0 * 16);
      short8 bk1 = *reinterpret_cast<const short8*>(sm + key * 128 + ph1 * 16);
      float4v S = zero;
      S = MFMA16(aq0, bk0, S);
      S = MFMA16(aq1, bk1, S);
#pragma unroll
      for (int r = 0; r < 4; ++r) {
        float e = __expf(S[r] * 0.125f);
        lsum[r] += e;
        *reinterpret_cast<short*>(sm + psOff + (quad * 4 + r) * 144 + key * 2) = bf16s(e);
      }
    }
    __builtin_amdgcn_s_waitcnt(0);  // P writes visible before P reads (same wave)
#pragma unroll
    for (int ks = 0; ks < 2; ++ks) {
      short8 ap = *reinterpret_cast<const short8*>(sm + psOff + lm * 144 + ks * 64 + quad * 16);
#pragma unroll
      for (int dt = 0; dt < 4; ++dt) {
        int dim = dt * 16 + lm;
        int ph = (ks * 4 + quad + dim) & 7;
        short8 bv = *reinterpret_cast<const short8*>(sm + 8192 + dim * 128 + ph * 16);
        accO[dt] = MFMA16(ap, bv, accO[dt]);
      }
    }
  }
#pragma unroll
  for (int r = 0; r < 4; ++r) {
    float l = lsum[r];
    l += __shfl_xor(l, 1); l += __shfl_xor(l, 2);
    l += __shfl_xor(l, 4); l += __shfl_xor(l, 8);
    lsum[r] = 1.f / l;
  }
  // transpose O through the Ps region for coalesced stores
#pragma unroll
  for (int dt = 0; dt < 4; ++dt)
#pragma unroll
    for (int r = 0; r < 4; ++r)
      *reinterpret_cast<short*>(sm + psOff + (quad * 4 + r) * 144 + (dt * 16 + lm) * 2) =
          bf16s(accO[dt][r] * lsum[r]);
  __builtin_amdgcn_s_waitcnt(0);
  int q2 = lane >> 2, c = lane & 3;
  int tok2 = sortq[sbase + n * 512 + qt * 64 + w * 16 + q2];
  __hip_bfloat16* op = ao + ((size_t)(b * 4096 + tok2) * 16 + h) * 64;
  short8 o0 = *reinterpret_cast<const short8*>(sm + psOff + q2 * 144 + c * 16);
  short8 o1 = *reinterpret_cast<const short8*>(sm + psOff + q2 * 144 + (c + 4) * 16);
  *reinterpret_cast<short8*>(op + c * 8) = o0;
  *reinterpret_cast<short8*>(op + (c + 4) * 8) = o1;
}

// ---------------------------------------------------------------------------
// loss_kernel: extra_loss = (sum_q + sum_k)/16 over (cnt/L)*(psum/L)
// ---------------------------------------------------------------------------
__global__ __launch_bounds__(1024) void loss_kernel(const int* __restrict__ cntg,
                                                    const float* __restrict__ psumg,
                                                    float* __restrict__ out) {
  int t = threadIdx.x;
  float term = ((float)cntg[t] * (1.f / 4096.f)) * (psumg[t] * (1.f / 4096.f));
#pragma unroll
  for (int o = 1; o < 64; o <<= 1) term += __shfl_xor(term, o);
  __shared__ float wsum[16];
  if ((t & 63) == 0) wsum[t >> 6] = term;
  __syncthreads();
  if (t == 0) {
    float s = 0.f;
    for (int i = 0; i < 16; ++i) s += wsum[i];
    out[16777216] = s * (1.f / 16.f);
  }
}

// ---------------------------------------------------------------------------
extern "C" void kernel_launch(void* const* d_in, const int* in_sizes, int n_in,
                              void* d_out, int out_size, void* d_ws, size_t ws_size,
                              hipStream_t stream) {
  (void)in_sizes; (void)n_in; (void)out_size; (void)ws_size;
  const float* x   = (const float*)d_in[0];
  const float* wq  = (const float*)d_in[1];
  const float* bq  = (const float*)d_in[2];
  const float* wk  = (const float*)d_in[3];
  const float* bk  = (const float*)d_in[4];
  const float* wv  = (const float*)d_in[5];
  const float* bv  = (const float*)d_in[6];
  const float* wsh = (const float*)d_in[7];
  const float* wqs = (const float*)d_in[8];
  const float* wks = (const float*)d_in[9];
  const float* wo  = (const float*)d_in[10];
  const float* bo  = (const float*)d_in[11];

  char* ws = (char*)d_ws;
  __hip_bfloat16* wt_qkv = (__hip_bfloat16*)(ws + 0);            // 6291456
  __hip_bfloat16* wt_o   = (__hip_bfloat16*)(ws + 6291456);      // 2097152
  double* wsc   = (double*)(ws + 8388608);                       // 2097152
  double* bsc   = (double*)(ws + 10485760);                      // 2048
  __hip_bfloat16* qkv  = (__hip_bfloat16*)(ws + 10487808);       // 3*33554432
  __hip_bfloat16* attn = (__hip_bfloat16*)(ws + 111151104);      // 33554432
  int* bid    = (int*)(ws + 144705536);                          // 2097152
  int* sortq  = (int*)(ws + 146802688);                          // 1048576
  int* sortk  = (int*)(ws + 147851264);                          // 1048576
  float* psumg = (float*)(ws + 148899840);                       // 4096
  int* cntg    = (int*)(ws + 148903936);                         // 4096
  __hip_bfloat16* vT = (__hip_bfloat16*)d_out;  // 33.5MB scratch inside out buf
  float* out = (float*)d_out;

  hipMemsetAsync(psumg, 0, 8192, stream);
  prep_wt<<<1024, 256, 0, stream>>>(wq, wk, wv, wo, wt_qkv, wt_o);
  prep_wsc<<<256, 256, 0, stream>>>(wq, wk, wsh, wqs, wks, bq, bk, wsc, bsc);
  score_kernel<<<256, 512, 0, stream>>>(x, wsc, bsc, bid, psumg);
  sort_kernel<<<128, 256, 0, stream>>>(bid, sortq, sortk, cntg);
  gemm_k<true><<<dim3(128, 24), 256, 0, stream>>>(x, wt_qkv, qkv, bq, bk, bv);
  vt_kernel<<<512, 256, 0, stream>>>(qkv + (size_t)2 * BL * 1024, sortk, vT);
  attn_kernel<<<4096, 256, 0, stream>>>(qkv, qkv + (size_t)BL * 1024, vT, sortq, sortk, attn);
  gemm_k<false><<<dim3(128, 8), 256, 0, stream>>>(attn, wt_o, (void*)out, bo, bo, bo);
  loss_kernel<<<1, 1024, 0, stream>>>(cntg, psumg, out);
}

// Round 3
// 794.414 us; speedup vs baseline: 1.8582x; 1.8582x over previous
//
#include <hip/hip_runtime.h>
#include <hip/hip_bf16.h>

// dims
#define BB 4
#define LL 4096
#define DM 1024
#define HH 16
#define DHD 64
#define KB 8
#define BL 16384  // BB*LL

typedef __attribute__((ext_vector_type(8))) short short8;
typedef __attribute__((ext_vector_type(4))) short short4v;
typedef __attribute__((ext_vector_type(4))) float float4v;

#define MFMA16(A, Bx, C) __builtin_amdgcn_mfma_f32_16x16x32_bf16(A, Bx, C, 0, 0, 0)

static __device__ __forceinline__ short bf16s(float f) {
  __hip_bfloat16 h = __float2bfloat16(f);
  return *reinterpret_cast<short*>(&h);
}

// ---------------------------------------------------------------------------
// prep_wt: transpose wq/wk/wv/wo ([k][n] fp32) -> [n][k] bf16
// ---------------------------------------------------------------------------
__global__ __launch_bounds__(256) void prep_wt(const float* __restrict__ wq,
                                               const float* __restrict__ wk,
                                               const float* __restrict__ wv,
                                               const float* __restrict__ wo,
                                               __hip_bfloat16* __restrict__ wt_qkv,
                                               __hip_bfloat16* __restrict__ wt_o) {
  int blk = blockIdx.x;
  int s = blk >> 8;
  int rem = blk & 255;
  int k0 = (rem >> 4) * 64;
  int n0 = (rem & 15) * 64;
  const float* src = (s == 0) ? wq : (s == 1) ? wk : (s == 2) ? wv : wo;
  __hip_bfloat16* dst = (s < 3) ? (wt_qkv + (size_t)s * 1024 * 1024) : wt_o;
  __shared__ float ls[64][65];
  int t = threadIdx.x;
#pragma unroll
  for (int p = 0; p < 4; ++p) {
    int sid = p * 256 + t;
    int r = sid >> 4, c4 = sid & 15;
    float4 v = *reinterpret_cast<const float4*>(src + (size_t)(k0 + r) * 1024 + n0 + c4 * 4);
    ls[r][c4 * 4 + 0] = v.x; ls[r][c4 * 4 + 1] = v.y;
    ls[r][c4 * 4 + 2] = v.z; ls[r][c4 * 4 + 3] = v.w;
  }
  __syncthreads();
#pragma unroll
  for (int p = 0; p < 4; ++p) {
    int sid = p * 256 + t;
    int n = sid >> 4, kq = sid & 15;
    short4v pk;
#pragma unroll
    for (int j = 0; j < 4; ++j) pk[j] = bf16s(ls[kq * 4 + j][n]);
    *reinterpret_cast<short4v*>(dst + (size_t)(n0 + n) * 1024 + k0 + kq * 4) = pk;
  }
}

// ---------------------------------------------------------------------------
// prep_wsc: fused score weights into wscg[g][d][kk] (fp64) and bias bsc[col].
// col = side*128 + h*8 + kk ; g = side*16 + h (so cols g*8..g*8+7 contiguous).
// grid 256 blocks (one col each), 256 threads
// ---------------------------------------------------------------------------
__global__ __launch_bounds__(256) void prep_wsc(const float* __restrict__ wq,
                                                const float* __restrict__ wk,
                                                const float* __restrict__ wsh,
                                                const float* __restrict__ wqs,
                                                const float* __restrict__ wks,
                                                const float* __restrict__ bq,
                                                const float* __restrict__ bk,
                                                double* __restrict__ wscg,
                                                double* __restrict__ bsc) {
  int col = blockIdx.x;
  int side = col >> 7, h = (col >> 3) & 15, kk = col & 7;
  int g = side * 16 + h;
  const float* w = side ? wk : wq;
  const float* wscore = side ? wks : wqs;
  __shared__ double mix[64];
  int t = threadIdx.x;
  if (t < 64)
    mix[t] = 0.9 * (double)wsh[(h * 64 + t) * 8 + kk] +
             0.1 * (double)wscore[(h * 64 + t) * 8 + kk];
  __syncthreads();
#pragma unroll
  for (int p = 0; p < 4; ++p) {
    int d = p * 256 + t;
    double acc = 0.0;
    const float* wr = w + (size_t)d * 1024 + h * 64;
#pragma unroll
    for (int j = 0; j < 64; ++j) acc += (double)wr[j] * mix[j];
    wscg[((size_t)g * 1024 + d) * 8 + kk] = acc;
  }
  if (t == 0) {
    const float* br = (side ? bk : bq) + h * 64;
    double acc = 0.0;
    for (int j = 0; j < 64; ++j) acc += (double)br[j] * mix[j];
    bsc[col] = acc;
  }
}

// ---------------------------------------------------------------------------
// score_kernel (rewritten): fp64 GEMM  C[16384,256] = X*Wsc + b, fused
// argmax->bid and softmax prob sums->psumg.
// Block 512 thr (8 waves): 64 tokens x 64 cols; lane=token, wave=8-col group.
// X tile staged in LDS (64x65 fp32, pad -> conflict-free); W via wave-uniform
// s_load streams from wscg[g][d][kk]. 8 fp64 acc/lane -> no spill.
// grid (256, 4)
// ---------------------------------------------------------------------------
__global__ __launch_bounds__(512) void score_kernel(const float* __restrict__ x,
                                                    const double* __restrict__ wscg,
                                                    const double* __restrict__ bsc,
                                                    int* __restrict__ bid,
                                                    float* __restrict__ psumg) {
  __shared__ float lsx[64 * 65];
  int t = threadIdx.x;
  int lane = t & 63;
  int g = __builtin_amdgcn_readfirstlane(blockIdx.y * 8 + (t >> 6));  // 0..31
  int T0 = blockIdx.x * 64;
  int b = T0 >> 12;
  int l = (T0 & 4095) + lane;  // token index within the (side,b,h) slab

  double acc[8];
#pragma unroll
  for (int j = 0; j < 8; ++j) acc[j] = bsc[g * 8 + j];

  for (int kc = 0; kc < 16; ++kc) {
    int k0 = kc * 64;
    __syncthreads();
#pragma unroll
    for (int p = 0; p < 2; ++p) {
      int sid = p * 512 + t;
      int row = sid >> 4, c = sid & 15;
      float4 v = *reinterpret_cast<const float4*>(x + (size_t)(T0 + row) * 1024 + k0 + c * 4);
      lsx[row * 65 + c * 4 + 0] = v.x;
      lsx[row * 65 + c * 4 + 1] = v.y;
      lsx[row * 65 + c * 4 + 2] = v.z;
      lsx[row * 65 + c * 4 + 3] = v.w;
    }
    __syncthreads();
    const double* wp = wscg + ((size_t)g * 1024 + k0) * 8;
#pragma unroll 4
    for (int d = 0; d < 64; ++d) {
      double xd = (double)lsx[lane * 65 + d];
#pragma unroll
      for (int j = 0; j < 8; ++j) acc[j] += xd * wp[d * 8 + j];
    }
  }

  // epilogue: argmax (first-max), bid write, softmax prob sums
  float v[8];
#pragma unroll
  for (int j = 0; j < 8; ++j) v[j] = (float)acc[j];
  float mx = v[0]; int am = 0;
#pragma unroll
  for (int j = 1; j < 8; ++j) { if (v[j] > mx) { mx = v[j]; am = j; } }
  float es = 0.f, e[8];
#pragma unroll
  for (int j = 0; j < 8; ++j) { e[j] = __expf(v[j] - mx); es += e[j]; }
  float inv = 1.f / es;
  int side = g >> 4, h = g & 15;
  int slab = (side * 4 + b) * 16 + h;
  bid[(slab << 12) + l] = am;
#pragma unroll
  for (int j = 0; j < 8; ++j) {
    float s = e[j] * inv;
    s += __shfl_xor(s, 1);  s += __shfl_xor(s, 2);  s += __shfl_xor(s, 4);
    s += __shfl_xor(s, 8);  s += __shfl_xor(s, 16); s += __shfl_xor(s, 32);
    if (lane == 0) atomicAdd(&psumg[slab * 8 + j], s);
  }
}

// ---------------------------------------------------------------------------
// sort_kernel: stable counting sort of 4096 tokens into 8 buckets per (side,b,h)
// ---------------------------------------------------------------------------
__global__ __launch_bounds__(256) void sort_kernel(const int* __restrict__ bid,
                                                   int* __restrict__ sortq,
                                                   int* __restrict__ sortk,
                                                   int* __restrict__ cntg) {
  int blk = blockIdx.x;
  int side = blk >> 6, b = (blk >> 4) & 3, h = blk & 15;
  const int* ids = bid + (((side * 4 + b) * 16 + h) << 12);
  int* outp = (side ? sortk : sortq) + ((b * 16 + h) << 12);
  __shared__ int cnt[8][257];
  __shared__ int base[8];
  int t = threadIdx.x;
  int loc[16];
  int hist[8] = {0, 0, 0, 0, 0, 0, 0, 0};
#pragma unroll
  for (int j = 0; j < 16; ++j) { loc[j] = ids[t * 16 + j] & 7; hist[loc[j]]++; }
#pragma unroll
  for (int k = 0; k < 8; ++k) cnt[k][t + 1] = hist[k];
  if (t < 8) cnt[t][0] = 0;
  __syncthreads();
  if (t < 8) {
    for (int i = 1; i <= 256; ++i) cnt[t][i] += cnt[t][i - 1];
  }
  __syncthreads();
  if (t == 0) {
    int run = 0;
    for (int k = 0; k < 8; ++k) { base[k] = run; run += cnt[k][256]; }
  }
  if (t < 8) cntg[((side * 4 + b) * 16 + h) * 8 + t] = cnt[t][256];
  __syncthreads();
#pragma unroll
  for (int j = 0; j < 16; ++j) {
    int k = loc[j];
    int before = 0;
#pragma unroll
    for (int i = 0; i < 16; ++i) before += (i < j && loc[i] == k) ? 1 : 0;
    int pos = base[k] + cnt[k][t] + before;
    outp[pos] = t * 16 + j;
  }
}

// ---------------------------------------------------------------------------
// gemm_k: C[M,N] = A[M,1024] * Bt[N,1024]^T (+bias). 128x128 tile, BK=64,
// 16x16x32 bf16 MFMA, swizzled LDS conflict-free.
// ---------------------------------------------------------------------------
template <bool AF32>
__global__ __launch_bounds__(256) void gemm_k(const void* __restrict__ Av,
                                              const __hip_bfloat16* __restrict__ Bt,
                                              void* __restrict__ Cv,
                                              const float* __restrict__ b0,
                                              const float* __restrict__ b1,
                                              const float* __restrict__ b2) {
  __shared__ char sm[32768];
  int t = threadIdx.x;
  int m0 = blockIdx.x * 128;
  int n0 = blockIdx.y * 128;
  int lane = t & 63, w = t >> 6;
  int lm = lane & 15, quad = lane >> 4;
  int wm = (w & 1) * 64, wn = (w >> 1) * 64;
  float4v zero = {0.f, 0.f, 0.f, 0.f};
  float4v acc[4][4];
#pragma unroll
  for (int i = 0; i < 4; ++i)
#pragma unroll
    for (int j = 0; j < 4; ++j) acc[i][j] = zero;

  for (int k0 = 0; k0 < 1024; k0 += 64) {
    __syncthreads();
#pragma unroll
    for (int p = 0; p < 4; ++p) {
      int sid = p * 256 + t;
      int m = sid >> 3, kc = sid & 7;
      short8 val;
      if constexpr (AF32) {
        const float* ap = (const float*)Av + (size_t)(m0 + m) * 1024 + k0 + kc * 8;
        float4 f0 = *reinterpret_cast<const float4*>(ap);
        float4 f1 = *reinterpret_cast<const float4*>(ap + 4);
        val[0] = bf16s(f0.x); val[1] = bf16s(f0.y); val[2] = bf16s(f0.z); val[3] = bf16s(f0.w);
        val[4] = bf16s(f1.x); val[5] = bf16s(f1.y); val[6] = bf16s(f1.z); val[7] = bf16s(f1.w);
      } else {
        val = *reinterpret_cast<const short8*>((const __hip_bfloat16*)Av +
                                               (size_t)(m0 + m) * 1024 + k0 + kc * 8);
      }
      *reinterpret_cast<short8*>(sm + m * 128 + ((kc + m) & 7) * 16) = val;
      short8 bvv = *reinterpret_cast<const short8*>(Bt + (size_t)(n0 + m) * 1024 + k0 + kc * 8);
      *reinterpret_cast<short8*>(sm + 16384 + m * 128 + ((kc + m) & 7) * 16) = bvv;
    }
    __syncthreads();
#pragma unroll
    for (int kh = 0; kh < 2; ++kh) {
      short8 af[4], bf[4];
#pragma unroll
      for (int i = 0; i < 4; ++i) {
        int row = wm + i * 16 + lm;
        int ph = ((kh * 4 + quad) + row) & 7;
        af[i] = *reinterpret_cast<const short8*>(sm + row * 128 + ph * 16);
        int rn = wn + i * 16 + lm;
        int phb = ((kh * 4 + quad) + rn) & 7;
        bf[i] = *reinterpret_cast<const short8*>(sm + 16384 + rn * 128 + phb * 16);
      }
#pragma unroll
      for (int i = 0; i < 4; ++i)
#pragma unroll
        for (int j = 0; j < 4; ++j) acc[i][j] = MFMA16(af[i], bf[j], acc[i][j]);
    }
  }

  if constexpr (AF32) {
    int s = n0 >> 10, nnb = n0 & 1023;
    const float* bias = (s == 0) ? b0 : (s == 1) ? b1 : b2;
    __hip_bfloat16* C = (__hip_bfloat16*)Cv + (size_t)s * BL * 1024;
#pragma unroll
    for (int i = 0; i < 4; ++i)
#pragma unroll
      for (int j = 0; j < 4; ++j) {
        int nn = nnb + wn + j * 16 + lm;
        float bvx = bias[nn];
#pragma unroll
        for (int r = 0; r < 4; ++r) {
          int row = m0 + wm + i * 16 + quad * 4 + r;
          C[(size_t)row * 1024 + nn] = __float2bfloat16(acc[i][j][r] + bvx);
        }
      }
  } else {
    float* C = (float*)Cv;
#pragma unroll
    for (int i = 0; i < 4; ++i)
#pragma unroll
      for (int j = 0; j < 4; ++j) {
        int gn = n0 + wn + j * 16 + lm;
        float bvx = b0[gn];
#pragma unroll
        for (int r = 0; r < 4; ++r) {
          int row = m0 + wm + i * 16 + quad * 4 + r;
          C[(size_t)row * 1024 + gn] = acc[i][j][r] + bvx;
        }
      }
  }
}

// ---------------------------------------------------------------------------
// vt_kernel: gather sorted V and transpose -> vT[cid][dim][key]
// ---------------------------------------------------------------------------
__global__ __launch_bounds__(256) void vt_kernel(const __hip_bfloat16* __restrict__ vb,
                                                 const int* __restrict__ sortk,
                                                 __hip_bfloat16* __restrict__ vT) {
  int cid = blockIdx.x;
  int b = cid >> 7, h = (cid >> 3) & 15, n = cid & 7;
  int sbase = ((b * 16 + h) << 12) + n * 512;
  __shared__ __hip_bfloat16 ls[64][72];
  int t = threadIdx.x;
  for (int kt = 0; kt < 8; ++kt) {
    __syncthreads();
#pragma unroll
    for (int p = 0; p < 2; ++p) {
      int sid = p * 256 + t;
      int key = sid >> 3, kc = sid & 7;
      int tok = sortk[sbase + kt * 64 + key];
      short8 v = *reinterpret_cast<const short8*>(vb + ((size_t)(b * 4096 + tok) * 16 + h) * 64 + kc * 8);
      *reinterpret_cast<short8*>(&ls[key][kc * 8]) = v;
    }
    __syncthreads();
#pragma unroll
    for (int p = 0; p < 2; ++p) {
      int sid = p * 256 + t;
      int dim = sid >> 3, kc = sid & 7;
      short8 o;
#pragma unroll
      for (int j = 0; j < 8; ++j) o[j] = *reinterpret_cast<short*>(&ls[kc * 8 + j][dim]);
      *reinterpret_cast<short8*>(vT + ((size_t)cid * 64 + dim) * 512 + kt * 64 + kc * 8) = o;
    }
  }
}

// ---------------------------------------------------------------------------
// attn_kernel: per (chunk, 64-query tile). Wave = 16 queries. K-tiles of 64.
// ---------------------------------------------------------------------------
__global__ __launch_bounds__(256) void attn_kernel(const __hip_bfloat16* __restrict__ qb,
                                                   const __hip_bfloat16* __restrict__ kb,
                                                   const __hip_bfloat16* __restrict__ vT,
                                                   const int* __restrict__ sortq,
                                                   const int* __restrict__ sortk,
                                                   __hip_bfloat16* __restrict__ ao) {
  __shared__ char sm[25600];  // Ks 8K | Vs 8K | Ps 4 waves x 16 x 144B
  int t = threadIdx.x;
  int lane = t & 63, w = t >> 6;
  int lm = lane & 15, quad = lane >> 4;
  int cid = blockIdx.x >> 3, qt = blockIdx.x & 7;
  int b = cid >> 7, h = (cid >> 3) & 15, n = cid & 7;
  int sbase = (b * 16 + h) << 12;
  int psOff = 16384 + w * 2304;

  int qtok = sortq[sbase + n * 512 + qt * 64 + w * 16 + lm];
  const __hip_bfloat16* qp = qb + ((size_t)(b * 4096 + qtok) * 16 + h) * 64 + quad * 8;
  short8 aq0 = *reinterpret_cast<const short8*>(qp);
  short8 aq1 = *reinterpret_cast<const short8*>(qp + 32);

  float4v zero = {0.f, 0.f, 0.f, 0.f};
  float4v accO[4];
#pragma unroll
  for (int i = 0; i < 4; ++i) accO[i] = zero;
  float lsum[4] = {0.f, 0.f, 0.f, 0.f};

  for (int kt = 0; kt < 8; ++kt) {
    __syncthreads();
#pragma unroll
    for (int p = 0; p < 2; ++p) {
      int sid = p * 256 + t;
      int row = sid >> 3, kc = sid & 7;
      int tok = sortk[sbase + n * 512 + kt * 64 + row];
      short8 kv = *reinterpret_cast<const short8*>(kb + ((size_t)(b * 4096 + tok) * 16 + h) * 64 + kc * 8);
      *reinterpret_cast<short8*>(sm + row * 128 + ((kc + row) & 7) * 16) = kv;
      short8 vv = *reinterpret_cast<const short8*>(vT + ((size_t)cid * 64 + row) * 512 + kt * 64 + kc * 8);
      *reinterpret_cast<short8*>(sm + 8192 + row * 128 + ((kc + row) & 7) * 16) = vv;
    }
    __syncthreads();
#pragma unroll
    for (int nt = 0; nt < 4; ++nt) {
      int key = nt * 16 + lm;
      int ph0 = (quad + key) & 7;
      int ph1 = (4 + quad + key) & 7;
      short8 bk0 = *reinterpret_cast<const short8*>(sm + key * 128 + ph0 * 16);
      short8 bk1 = *reinterpret_cast<const short8*>(sm + key * 128 + ph1 * 16);
      float4v S = zero;
      S = MFMA16(aq0, bk0, S);
      S = MFMA16(aq1, bk1, S);
#pragma unroll
      for (int r = 0; r < 4; ++r) {
        float e = __expf(S[r] * 0.125f);
        lsum[r] += e;
        *reinterpret_cast<short*>(sm + psOff + (quad * 4 + r) * 144 + key * 2) = bf16s(e);
      }
    }
    __builtin_amdgcn_s_waitcnt(0);  // P writes visible before P reads (same wave)
#pragma unroll
    for (int ks = 0; ks < 2; ++ks) {
      short8 ap = *reinterpret_cast<const short8*>(sm + psOff + lm * 144 + ks * 64 + quad * 16);
#pragma unroll
      for (int dt = 0; dt < 4; ++dt) {
        int dim = dt * 16 + lm;
        int ph = (ks * 4 + quad + dim) & 7;
        short8 bv = *reinterpret_cast<const short8*>(sm + 8192 + dim * 128 + ph * 16);
        accO[dt] = MFMA16(ap, bv, accO[dt]);
      }
    }
  }
#pragma unroll
  for (int r = 0; r < 4; ++r) {
    float l = lsum[r];
    l += __shfl_xor(l, 1); l += __shfl_xor(l, 2);
    l += __shfl_xor(l, 4); l += __shfl_xor(l, 8);
    lsum[r] = 1.f / l;
  }
  // transpose O through the Ps region for coalesced stores
#pragma unroll
  for (int dt = 0; dt < 4; ++dt)
#pragma unroll
    for (int r = 0; r < 4; ++r)
      *reinterpret_cast<short*>(sm + psOff + (quad * 4 + r) * 144 + (dt * 16 + lm) * 2) =
          bf16s(accO[dt][r] * lsum[r]);
  __builtin_amdgcn_s_waitcnt(0);
  int q2 = lane >> 2, c = lane & 3;
  int tok2 = sortq[sbase + n * 512 + qt * 64 + w * 16 + q2];
  __hip_bfloat16* op = ao + ((size_t)(b * 4096 + tok2) * 16 + h) * 64;
  short8 o0 = *reinterpret_cast<const short8*>(sm + psOff + q2 * 144 + c * 16);
  short8 o1 = *reinterpret_cast<const short8*>(sm + psOff + q2 * 144 + (c + 4) * 16);
  *reinterpret_cast<short8*>(op + c * 8) = o0;
  *reinterpret_cast<short8*>(op + (c + 4) * 8) = o1;
}

// ---------------------------------------------------------------------------
// loss_kernel: extra_loss = (sum_q + sum_k)/16 over (cnt/L)*(psum/L)
// ---------------------------------------------------------------------------
__global__ __launch_bounds__(1024) void loss_kernel(const int* __restrict__ cntg,
                                                    const float* __restrict__ psumg,
                                                    float* __restrict__ out) {
  int t = threadIdx.x;
  float term = ((float)cntg[t] * (1.f / 4096.f)) * (psumg[t] * (1.f / 4096.f));
#pragma unroll
  for (int o = 1; o < 64; o <<= 1) term += __shfl_xor(term, o);
  __shared__ float wsum[16];
  if ((t & 63) == 0) wsum[t >> 6] = term;
  __syncthreads();
  if (t == 0) {
    float s = 0.f;
    for (int i = 0; i < 16; ++i) s += wsum[i];
    out[16777216] = s * (1.f / 16.f);
  }
}

// ---------------------------------------------------------------------------
extern "C" void kernel_launch(void* const* d_in, const int* in_sizes, int n_in,
                              void* d_out, int out_size, void* d_ws, size_t ws_size,
                              hipStream_t stream) {
  (void)in_sizes; (void)n_in; (void)out_size; (void)ws_size;
  const float* x   = (const float*)d_in[0];
  const float* wq  = (const float*)d_in[1];
  const float* bq  = (const float*)d_in[2];
  const float* wk  = (const float*)d_in[3];
  const float* bk  = (const float*)d_in[4];
  const float* wv  = (const float*)d_in[5];
  const float* bv  = (const float*)d_in[6];
  const float* wsh = (const float*)d_in[7];
  const float* wqs = (const float*)d_in[8];
  const float* wks = (const float*)d_in[9];
  const float* wo  = (const float*)d_in[10];
  const float* bo  = (const float*)d_in[11];

  char* ws = (char*)d_ws;
  __hip_bfloat16* wt_qkv = (__hip_bfloat16*)(ws + 0);            // 6291456
  __hip_bfloat16* wt_o   = (__hip_bfloat16*)(ws + 6291456);      // 2097152
  double* wscg  = (double*)(ws + 8388608);                       // 2097152
  double* bsc   = (double*)(ws + 10485760);                      // 2048
  __hip_bfloat16* qkv  = (__hip_bfloat16*)(ws + 10487808);       // 3*33554432
  __hip_bfloat16* attn = (__hip_bfloat16*)(ws + 111151104);      // 33554432
  int* bid    = (int*)(ws + 144705536);                          // 2097152
  int* sortq  = (int*)(ws + 146802688);                          // 1048576
  int* sortk  = (int*)(ws + 147851264);                          // 1048576
  float* psumg = (float*)(ws + 148899840);                       // 4096
  int* cntg    = (int*)(ws + 148903936);                         // 4096
  __hip_bfloat16* vT = (__hip_bfloat16*)d_out;  // 33.5MB scratch inside out buf
  float* out = (float*)d_out;

  hipMemsetAsync(psumg, 0, 8192, stream);
  prep_wt<<<1024, 256, 0, stream>>>(wq, wk, wv, wo, wt_qkv, wt_o);
  prep_wsc<<<256, 256, 0, stream>>>(wq, wk, wsh, wqs, wks, bq, bk, wscg, bsc);
  score_kernel<<<dim3(256, 4), 512, 0, stream>>>(x, wscg, bsc, bid, psumg);
  sort_kernel<<<128, 256, 0, stream>>>(bid, sortq, sortk, cntg);
  gemm_k<true><<<dim3(128, 24), 256, 0, stream>>>(x, wt_qkv, qkv, bq, bk, bv);
  vt_kernel<<<512, 256, 0, stream>>>(qkv + (size_t)2 * BL * 1024, sortk, vT);
  attn_kernel<<<4096, 256, 0, stream>>>(qkv, qkv + (size_t)BL * 1024, vT, sortq, sortk, attn);
  gemm_k<false><<<dim3(128, 8), 256, 0, stream>>>(attn, wt_o, (void*)out, bo, bo, bo);
  loss_kernel<<<1, 1024, 0, stream>>>(cntg, psumg, out);
}

// Round 4
// 610.122 us; speedup vs baseline: 2.4195x; 1.3021x over previous
//
#include <hip/hip_runtime.h>
#include <hip/hip_bf16.h>

// dims
#define BB 4
#define LL 4096
#define DM 1024
#define HH 16
#define DHD 64
#define KB 8
#define BL 16384  // BB*LL
#define FLAGCAP 131072

typedef __attribute__((ext_vector_type(8))) short short8;
typedef __attribute__((ext_vector_type(4))) short short4v;
typedef __attribute__((ext_vector_type(4))) float float4v;

#define MFMA16(A, Bx, C) __builtin_amdgcn_mfma_f32_16x16x32_bf16(A, Bx, C, 0, 0, 0)

static __device__ __forceinline__ short bf16s(float f) {
  __hip_bfloat16 h = __float2bfloat16(f);
  return *reinterpret_cast<short*>(&h);
}
static __device__ __forceinline__ float b2f(short s) {
  __hip_bfloat16 h = *reinterpret_cast<__hip_bfloat16*>(&s);
  return __bfloat162float(h);
}

// ---------------------------------------------------------------------------
// prep_wt: transpose wq/wk/wv/wo ([k][n] fp32) -> [n][k] bf16
// ---------------------------------------------------------------------------
__global__ __launch_bounds__(256) void prep_wt(const float* __restrict__ wq,
                                               const float* __restrict__ wk,
                                               const float* __restrict__ wv,
                                               const float* __restrict__ wo,
                                               __hip_bfloat16* __restrict__ wt_qkv,
                                               __hip_bfloat16* __restrict__ wt_o) {
  int blk = blockIdx.x;
  int s = blk >> 8;
  int rem = blk & 255;
  int k0 = (rem >> 4) * 64;
  int n0 = (rem & 15) * 64;
  const float* src = (s == 0) ? wq : (s == 1) ? wk : (s == 2) ? wv : wo;
  __hip_bfloat16* dst = (s < 3) ? (wt_qkv + (size_t)s * 1024 * 1024) : wt_o;
  __shared__ float ls[64][65];
  int t = threadIdx.x;
#pragma unroll
  for (int p = 0; p < 4; ++p) {
    int sid = p * 256 + t;
    int r = sid >> 4, c4 = sid & 15;
    float4 v = *reinterpret_cast<const float4*>(src + (size_t)(k0 + r) * 1024 + n0 + c4 * 4);
    ls[r][c4 * 4 + 0] = v.x; ls[r][c4 * 4 + 1] = v.y;
    ls[r][c4 * 4 + 2] = v.z; ls[r][c4 * 4 + 3] = v.w;
  }
  __syncthreads();
#pragma unroll
  for (int p = 0; p < 4; ++p) {
    int sid = p * 256 + t;
    int n = sid >> 4, kq = sid & 15;
    short4v pk;
#pragma unroll
    for (int j = 0; j < 4; ++j) pk[j] = bf16s(ls[kq * 4 + j][n]);
    *reinterpret_cast<short4v*>(dst + (size_t)(n0 + n) * 1024 + k0 + kq * 4) = pk;
  }
}

// ---------------------------------------------------------------------------
// prep_wsc: fused score weights. Outputs:
//   wscg[g][d][kk] fp64 (refine), bsc[col] fp64,
//   whb/wmb [col][d] bf16 hi/mid split (score_gemm B operand).
// col = side*128 + h*8 + kk ; g = side*16 + h. grid 256 blocks, 256 thr.
// ---------------------------------------------------------------------------
__global__ __launch_bounds__(256) void prep_wsc(const float* __restrict__ wq,
                                                const float* __restrict__ wk,
                                                const float* __restrict__ wsh,
                                                const float* __restrict__ wqs,
                                                const float* __restrict__ wks,
                                                const float* __restrict__ bq,
                                                const float* __restrict__ bk,
                                                double* __restrict__ wscg,
                                                double* __restrict__ bsc,
                                                __hip_bfloat16* __restrict__ whb,
                                                __hip_bfloat16* __restrict__ wmb) {
  int col = blockIdx.x;
  int side = col >> 7, h = (col >> 3) & 15, kk = col & 7;
  int g = side * 16 + h;
  const float* w = side ? wk : wq;
  const float* wscore = side ? wks : wqs;
  __shared__ double mix[64];
  int t = threadIdx.x;
  if (t < 64)
    mix[t] = 0.9 * (double)wsh[(h * 64 + t) * 8 + kk] +
             0.1 * (double)wscore[(h * 64 + t) * 8 + kk];
  __syncthreads();
#pragma unroll
  for (int p = 0; p < 4; ++p) {
    int d = p * 256 + t;
    double acc = 0.0;
    const float* wr = w + (size_t)d * 1024 + h * 64;
#pragma unroll
    for (int j = 0; j < 64; ++j) acc += (double)wr[j] * mix[j];
    wscg[((size_t)g * 1024 + d) * 8 + kk] = acc;
    short hi = bf16s((float)acc);
    short mid = bf16s((float)(acc - (double)b2f(hi)));
    *reinterpret_cast<short*>(whb + (size_t)col * 1024 + d) = hi;
    *reinterpret_cast<short*>(wmb + (size_t)col * 1024 + d) = mid;
  }
  if (t == 0) {
    const float* br = (side ? bk : bq) + h * 64;
    double acc = 0.0;
    for (int j = 0; j < 64; ++j) acc += (double)br[j] * mix[j];
    bsc[col] = acc;
  }
}

// ---------------------------------------------------------------------------
// score_gemm: S[t][col] = x*Wsc + b via bf16-split MFMA:
//   S ~= xh*wh + xh*wm + xl*wh  (error ~1e-6 << refine threshold 5e-4)
// Tile M=64 x N=128, BK=64. Output layout S2[g][t][kk] (g=col>>3, kk=col&7).
// grid (256, 2), 256 thr.
// ---------------------------------------------------------------------------
__global__ __launch_bounds__(256) void score_gemm(const float* __restrict__ x,
                                                  const __hip_bfloat16* __restrict__ whb,
                                                  const __hip_bfloat16* __restrict__ wmb,
                                                  const double* __restrict__ bsc,
                                                  float* __restrict__ S2) {
  __shared__ char sm[49152];  // xh 8K | xl 8K | wh 16K | wm 16K
  int t = threadIdx.x;
  int m0 = blockIdx.x * 64;
  int n0 = blockIdx.y * 128;
  int lane = t & 63, w = t >> 6;
  int lm = lane & 15, quad = lane >> 4;
  int wmr = (w & 1) * 32, wn = (w >> 1) * 64;
  float4v zero = {0.f, 0.f, 0.f, 0.f};
  float4v acc[2][4];
#pragma unroll
  for (int i = 0; i < 2; ++i)
#pragma unroll
    for (int j = 0; j < 4; ++j) acc[i][j] = zero;

  for (int k0 = 0; k0 < 1024; k0 += 64) {
    __syncthreads();
#pragma unroll
    for (int p = 0; p < 2; ++p) {  // A: 64 rows x 8 kc
      int sid = p * 256 + t;
      int m = sid >> 3, kc = sid & 7;
      const float* ap = x + (size_t)(m0 + m) * 1024 + k0 + kc * 8;
      float4 f0 = *reinterpret_cast<const float4*>(ap);
      float4 f1 = *reinterpret_cast<const float4*>(ap + 4);
      float vv[8] = {f0.x, f0.y, f0.z, f0.w, f1.x, f1.y, f1.z, f1.w};
      short8 hi, lo;
#pragma unroll
      for (int e = 0; e < 8; ++e) {
        short h = bf16s(vv[e]);
        hi[e] = h;
        lo[e] = bf16s(vv[e] - b2f(h));
      }
      *reinterpret_cast<short8*>(sm + m * 128 + ((kc + m) & 7) * 16) = hi;
      *reinterpret_cast<short8*>(sm + 8192 + m * 128 + ((kc + m) & 7) * 16) = lo;
    }
#pragma unroll
    for (int p = 0; p < 4; ++p) {  // B: 128 rows x 8 kc
      int sid = p * 256 + t;
      int n = sid >> 3, kc = sid & 7;
      short8 bh = *reinterpret_cast<const short8*>(whb + (size_t)(n0 + n) * 1024 + k0 + kc * 8);
      short8 bm = *reinterpret_cast<const short8*>(wmb + (size_t)(n0 + n) * 1024 + k0 + kc * 8);
      *reinterpret_cast<short8*>(sm + 16384 + n * 128 + ((kc + n) & 7) * 16) = bh;
      *reinterpret_cast<short8*>(sm + 32768 + n * 128 + ((kc + n) & 7) * 16) = bm;
    }
    __syncthreads();
#pragma unroll
    for (int kh = 0; kh < 2; ++kh) {
      short8 ah[2], al[2], bh[4], bm[4];
#pragma unroll
      for (int i = 0; i < 2; ++i) {
        int row = wmr + i * 16 + lm;
        int ph = ((kh * 4 + quad) + row) & 7;
        ah[i] = *reinterpret_cast<const short8*>(sm + row * 128 + ph * 16);
        al[i] = *reinterpret_cast<const short8*>(sm + 8192 + row * 128 + ph * 16);
      }
#pragma unroll
      for (int j = 0; j < 4; ++j) {
        int rn = wn + j * 16 + lm;
        int ph = ((kh * 4 + quad) + rn) & 7;
        bh[j] = *reinterpret_cast<const short8*>(sm + 16384 + rn * 128 + ph * 16);
        bm[j] = *reinterpret_cast<const short8*>(sm + 32768 + rn * 128 + ph * 16);
      }
#pragma unroll
      for (int i = 0; i < 2; ++i)
#pragma unroll
        for (int j = 0; j < 4; ++j) {
          acc[i][j] = MFMA16(ah[i], bh[j], acc[i][j]);
          acc[i][j] = MFMA16(ah[i], bm[j], acc[i][j]);
          acc[i][j] = MFMA16(al[i], bh[j], acc[i][j]);
        }
    }
  }

#pragma unroll
  for (int i = 0; i < 2; ++i)
#pragma unroll
    for (int j = 0; j < 4; ++j) {
      int n = n0 + wn + j * 16 + lm;
      float bias = (float)bsc[n];
#pragma unroll
      for (int r = 0; r < 4; ++r) {
        int row = m0 + wmr + i * 16 + quad * 4 + r;
        S2[(size_t)(n >> 3) * 131072 + row * 8 + (n & 7)] = acc[i][j][r] + bias;
      }
    }
}

// ---------------------------------------------------------------------------
// bucket_kernel: per (token, g): argmax -> bid, softmax prob sums -> psumg,
// flag near-ties (gap < 5e-4) for fp64 refine. grid 256 x 512 thr.
// ---------------------------------------------------------------------------
__global__ __launch_bounds__(512) void bucket_kernel(const float* __restrict__ S2,
                                                     int* __restrict__ bid,
                                                     float* __restrict__ psumg,
                                                     int* __restrict__ flagcnt,
                                                     int* __restrict__ list) {
  int t = threadIdx.x;
  int lane = t & 63;
  int w = t >> 6;
  int T0 = blockIdx.x * 64;
  int tg = T0 + lane;
  int b = tg >> 12, l = tg & 4095;
#pragma unroll
  for (int gi = 0; gi < 4; ++gi) {
    int g = gi * 8 + w;
    const float* sp = S2 + (size_t)g * 131072 + tg * 8;
    float4 v0 = *reinterpret_cast<const float4*>(sp);
    float4 v1 = *reinterpret_cast<const float4*>(sp + 4);
    float v[8] = {v0.x, v0.y, v0.z, v0.w, v1.x, v1.y, v1.z, v1.w};
    float mx = v[0]; int am = 0;
#pragma unroll
    for (int j = 1; j < 8; ++j) { if (v[j] > mx) { mx = v[j]; am = j; } }
    float mx2 = -3.0e38f;
#pragma unroll
    for (int j = 0; j < 8; ++j) { if (j != am && v[j] > mx2) mx2 = v[j]; }
    int side = g >> 4, h = g & 15;
    int slab = (side * 4 + b) * 16 + h;
    bid[(slab << 12) | l] = am;
    if (mx - mx2 < 5e-4f) {
      int pos = atomicAdd(flagcnt, 1);
      if (pos < FLAGCAP) list[pos] = (slab << 12) | l;
    }
    float es = 0.f, e[8];
#pragma unroll
    for (int j = 0; j < 8; ++j) { e[j] = __expf(v[j] - mx); es += e[j]; }
    float inv = 1.f / es;
#pragma unroll
    for (int j = 0; j < 8; ++j) {
      float s = e[j] * inv;
      s += __shfl_xor(s, 1);  s += __shfl_xor(s, 2);  s += __shfl_xor(s, 4);
      s += __shfl_xor(s, 8);  s += __shfl_xor(s, 16); s += __shfl_xor(s, 32);
      if (lane == 0) atomicAdd(&psumg[slab * 8 + j], s);
    }
  }
}

// ---------------------------------------------------------------------------
// refine_kernel: exact fp64 scores for flagged tokens; overwrite bid.
// One wave per entry; lane = 16-wide k-slice. grid 256 x 256 thr.
// ---------------------------------------------------------------------------
__global__ __launch_bounds__(256) void refine_kernel(const float* __restrict__ x,
                                                     const double* __restrict__ wscg,
                                                     const double* __restrict__ bsc,
                                                     const int* __restrict__ flagcnt,
                                                     const int* __restrict__ list,
                                                     int* __restrict__ bid) {
  int lane = threadIdx.x & 63;
  int w = threadIdx.x >> 6;
  int cnt = flagcnt[0];
  if (cnt > FLAGCAP) cnt = FLAGCAP;
  for (int i = blockIdx.x * 4 + w; i < cnt; i += 1024) {
    int e = list[i];
    int slab = e >> 12, l = e & 4095;
    int side = slab >> 6, b = (slab >> 4) & 3, h = slab & 15;
    int g = side * 16 + h;
    int row = b * 4096 + l;
    double acc[8] = {0, 0, 0, 0, 0, 0, 0, 0};
    const float* xr = x + (size_t)row * 1024 + lane * 16;
    const double* wr = wscg + ((size_t)g * 1024 + lane * 16) * 8;
#pragma unroll
    for (int dd = 0; dd < 16; ++dd) {
      double xv = (double)xr[dd];
#pragma unroll
      for (int j = 0; j < 8; ++j) acc[j] += xv * wr[dd * 8 + j];
    }
#pragma unroll
    for (int j = 0; j < 8; ++j) {
      double v = acc[j];
      v += __shfl_xor(v, 32); v += __shfl_xor(v, 16); v += __shfl_xor(v, 8);
      v += __shfl_xor(v, 4);  v += __shfl_xor(v, 2);  v += __shfl_xor(v, 1);
      acc[j] = v + bsc[g * 8 + j];
    }
    if (lane == 0) {
      double mx = acc[0]; int am = 0;
#pragma unroll
      for (int j = 1; j < 8; ++j) { if (acc[j] > mx) { mx = acc[j]; am = j; } }
      bid[(slab << 12) | l] = am;
    }
  }
}

// ---------------------------------------------------------------------------
// sort_kernel: stable counting sort of 4096 tokens into 8 buckets per (side,b,h)
// ---------------------------------------------------------------------------
__global__ __launch_bounds__(256) void sort_kernel(const int* __restrict__ bid,
                                                   int* __restrict__ sortq,
                                                   int* __restrict__ sortk,
                                                   int* __restrict__ cntg) {
  int blk = blockIdx.x;
  int side = blk >> 6, b = (blk >> 4) & 3, h = blk & 15;
  const int* ids = bid + (((side * 4 + b) * 16 + h) << 12);
  int* outp = (side ? sortk : sortq) + ((b * 16 + h) << 12);
  __shared__ int cnt[8][257];
  __shared__ int base[8];
  int t = threadIdx.x;
  int loc[16];
  int hist[8] = {0, 0, 0, 0, 0, 0, 0, 0};
#pragma unroll
  for (int j = 0; j < 16; ++j) { loc[j] = ids[t * 16 + j] & 7; hist[loc[j]]++; }
#pragma unroll
  for (int k = 0; k < 8; ++k) cnt[k][t + 1] = hist[k];
  if (t < 8) cnt[t][0] = 0;
  __syncthreads();
  if (t < 8) {
    for (int i = 1; i <= 256; ++i) cnt[t][i] += cnt[t][i - 1];
  }
  __syncthreads();
  if (t == 0) {
    int run = 0;
    for (int k = 0; k < 8; ++k) { base[k] = run; run += cnt[k][256]; }
  }
  if (t < 8) cntg[((side * 4 + b) * 16 + h) * 8 + t] = cnt[t][256];
  __syncthreads();
#pragma unroll
  for (int j = 0; j < 16; ++j) {
    int k = loc[j];
    int before = 0;
#pragma unroll
    for (int i = 0; i < 16; ++i) before += (i < j && loc[i] == k) ? 1 : 0;
    int pos = base[k] + cnt[k][t] + before;
    outp[pos] = t * 16 + j;
  }
}

// ---------------------------------------------------------------------------
// gemm_k: C[M,N] = A[M,1024] * Bt[N,1024]^T (+bias). 128x128 tile, BK=64.
// ---------------------------------------------------------------------------
template <bool AF32>
__global__ __launch_bounds__(256) void gemm_k(const void* __restrict__ Av,
                                              const __hip_bfloat16* __restrict__ Bt,
                                              void* __restrict__ Cv,
                                              const float* __restrict__ b0,
                                              const float* __restrict__ b1,
                                              const float* __restrict__ b2) {
  __shared__ char sm[32768];
  int t = threadIdx.x;
  int m0 = blockIdx.x * 128;
  int n0 = blockIdx.y * 128;
  int lane = t & 63, w = t >> 6;
  int lm = lane & 15, quad = lane >> 4;
  int wm = (w & 1) * 64, wn = (w >> 1) * 64;
  float4v zero = {0.f, 0.f, 0.f, 0.f};
  float4v acc[4][4];
#pragma unroll
  for (int i = 0; i < 4; ++i)
#pragma unroll
    for (int j = 0; j < 4; ++j) acc[i][j] = zero;

  for (int k0 = 0; k0 < 1024; k0 += 64) {
    __syncthreads();
#pragma unroll
    for (int p = 0; p < 4; ++p) {
      int sid = p * 256 + t;
      int m = sid >> 3, kc = sid & 7;
      short8 val;
      if constexpr (AF32) {
        const float* ap = (const float*)Av + (size_t)(m0 + m) * 1024 + k0 + kc * 8;
        float4 f0 = *reinterpret_cast<const float4*>(ap);
        float4 f1 = *reinterpret_cast<const float4*>(ap + 4);
        val[0] = bf16s(f0.x); val[1] = bf16s(f0.y); val[2] = bf16s(f0.z); val[3] = bf16s(f0.w);
        val[4] = bf16s(f1.x); val[5] = bf16s(f1.y); val[6] = bf16s(f1.z); val[7] = bf16s(f1.w);
      } else {
        val = *reinterpret_cast<const short8*>((const __hip_bfloat16*)Av +
                                               (size_t)(m0 + m) * 1024 + k0 + kc * 8);
      }
      *reinterpret_cast<short8*>(sm + m * 128 + ((kc + m) & 7) * 16) = val;
      short8 bvv = *reinterpret_cast<const short8*>(Bt + (size_t)(n0 + m) * 1024 + k0 + kc * 8);
      *reinterpret_cast<short8*>(sm + 16384 + m * 128 + ((kc + m) & 7) * 16) = bvv;
    }
    __syncthreads();
#pragma unroll
    for (int kh = 0; kh < 2; ++kh) {
      short8 af[4], bf[4];
#pragma unroll
      for (int i = 0; i < 4; ++i) {
        int row = wm + i * 16 + lm;
        int ph = ((kh * 4 + quad) + row) & 7;
        af[i] = *reinterpret_cast<const short8*>(sm + row * 128 + ph * 16);
        int rn = wn + i * 16 + lm;
        int phb = ((kh * 4 + quad) + rn) & 7;
        bf[i] = *reinterpret_cast<const short8*>(sm + 16384 + rn * 128 + phb * 16);
      }
#pragma unroll
      for (int i = 0; i < 4; ++i)
#pragma unroll
        for (int j = 0; j < 4; ++j) acc[i][j] = MFMA16(af[i], bf[j], acc[i][j]);
    }
  }

  if constexpr (AF32) {
    int s = n0 >> 10, nnb = n0 & 1023;
    const float* bias = (s == 0) ? b0 : (s == 1) ? b1 : b2;
    __hip_bfloat16* C = (__hip_bfloat16*)Cv + (size_t)s * BL * 1024;
#pragma unroll
    for (int i = 0; i < 4; ++i)
#pragma unroll
      for (int j = 0; j < 4; ++j) {
        int nn = nnb + wn + j * 16 + lm;
        float bvx = bias[nn];
#pragma unroll
        for (int r = 0; r < 4; ++r) {
          int row = m0 + wm + i * 16 + quad * 4 + r;
          C[(size_t)row * 1024 + nn] = __float2bfloat16(acc[i][j][r] + bvx);
        }
      }
  } else {
    float* C = (float*)Cv;
#pragma unroll
    for (int i = 0; i < 4; ++i)
#pragma unroll
      for (int j = 0; j < 4; ++j) {
        int gn = n0 + wn + j * 16 + lm;
        float bvx = b0[gn];
#pragma unroll
        for (int r = 0; r < 4; ++r) {
          int row = m0 + wm + i * 16 + quad * 4 + r;
          C[(size_t)row * 1024 + gn] = acc[i][j][r] + bvx;
        }
      }
  }
}

// ---------------------------------------------------------------------------
// vt_kernel: gather sorted V and transpose -> vT[cid][dim][key]
// ---------------------------------------------------------------------------
__global__ __launch_bounds__(256) void vt_kernel(const __hip_bfloat16* __restrict__ vb,
                                                 const int* __restrict__ sortk,
                                                 __hip_bfloat16* __restrict__ vT) {
  int cid = blockIdx.x;
  int b = cid >> 7, h = (cid >> 3) & 15, n = cid & 7;
  int sbase = ((b * 16 + h) << 12) + n * 512;
  __shared__ __hip_bfloat16 ls[64][72];
  int t = threadIdx.x;
  for (int kt = 0; kt < 8; ++kt) {
    __syncthreads();
#pragma unroll
    for (int p = 0; p < 2; ++p) {
      int sid = p * 256 + t;
      int key = sid >> 3, kc = sid & 7;
      int tok = sortk[sbase + kt * 64 + key];
      short8 v = *reinterpret_cast<const short8*>(vb + ((size_t)(b * 4096 + tok) * 16 + h) * 64 + kc * 8);
      *reinterpret_cast<short8*>(&ls[key][kc * 8]) = v;
    }
    __syncthreads();
#pragma unroll
    for (int p = 0; p < 2; ++p) {
      int sid = p * 256 + t;
      int dim = sid >> 3, kc = sid & 7;
      short8 o;
#pragma unroll
      for (int j = 0; j < 8; ++j) o[j] = *reinterpret_cast<short*>(&ls[kc * 8 + j][dim]);
      *reinterpret_cast<short8*>(vT + ((size_t)cid * 64 + dim) * 512 + kt * 64 + kc * 8) = o;
    }
  }
}

// ---------------------------------------------------------------------------
// attn_kernel: per (chunk, 64-query tile). Wave = 16 queries. K-tiles of 64.
// ---------------------------------------------------------------------------
__global__ __launch_bounds__(256) void attn_kernel(const __hip_bfloat16* __restrict__ qb,
                                                   const __hip_bfloat16* __restrict__ kb,
                                                   const __hip_bfloat16* __restrict__ vT,
                                                   const int* __restrict__ sortq,
                                                   const int* __restrict__ sortk,
                                                   __hip_bfloat16* __restrict__ ao) {
  __shared__ char sm[25600];  // Ks 8K | Vs 8K | Ps 4 waves x 16 x 144B
  int t = threadIdx.x;
  int lane = t & 63, w = t >> 6;
  int lm = lane & 15, quad = lane >> 4;
  int cid = blockIdx.x >> 3, qt = blockIdx.x & 7;
  int b = cid >> 7, h = (cid >> 3) & 15, n = cid & 7;
  int sbase = (b * 16 + h) << 12;
  int psOff = 16384 + w * 2304;

  int qtok = sortq[sbase + n * 512 + qt * 64 + w * 16 + lm];
  const __hip_bfloat16* qp = qb + ((size_t)(b * 4096 + qtok) * 16 + h) * 64 + quad * 8;
  short8 aq0 = *reinterpret_cast<const short8*>(qp);
  short8 aq1 = *reinterpret_cast<const short8*>(qp + 32);

  float4v zero = {0.f, 0.f, 0.f, 0.f};
  float4v accO[4];
#pragma unroll
  for (int i = 0; i < 4; ++i) accO[i] = zero;
  float lsum[4] = {0.f, 0.f, 0.f, 0.f};

  for (int kt = 0; kt < 8; ++kt) {
    __syncthreads();
#pragma unroll
    for (int p = 0; p < 2; ++p) {
      int sid = p * 256 + t;
      int row = sid >> 3, kc = sid & 7;
      int tok = sortk[sbase + n * 512 + kt * 64 + row];
      short8 kv = *reinterpret_cast<const short8*>(kb + ((size_t)(b * 4096 + tok) * 16 + h) * 64 + kc * 8);
      *reinterpret_cast<short8*>(sm + row * 128 + ((kc + row) & 7) * 16) = kv;
      short8 vv = *reinterpret_cast<const short8*>(vT + ((size_t)cid * 64 + row) * 512 + kt * 64 + kc * 8);
      *reinterpret_cast<short8*>(sm + 8192 + row * 128 + ((kc + row) & 7) * 16) = vv;
    }
    __syncthreads();
#pragma unroll
    for (int nt = 0; nt < 4; ++nt) {
      int key = nt * 16 + lm;
      int ph0 = (quad + key) & 7;
      int ph1 = (4 + quad + key) & 7;
      short8 bk0 = *reinterpret_cast<const short8*>(sm + key * 128 + ph0 * 16);
      short8 bk1 = *reinterpret_cast<const short8*>(sm + key * 128 + ph1 * 16);
      float4v S = zero;
      S = MFMA16(aq0, bk0, S);
      S = MFMA16(aq1, bk1, S);
#pragma unroll
      for (int r = 0; r < 4; ++r) {
        float e = __expf(S[r] * 0.125f);
        lsum[r] += e;
        *reinterpret_cast<short*>(sm + psOff + (quad * 4 + r) * 144 + key * 2) = bf16s(e);
      }
    }
    __builtin_amdgcn_s_waitcnt(0);  // P writes visible before P reads (same wave)
#pragma unroll
    for (int ks = 0; ks < 2; ++ks) {
      short8 ap = *reinterpret_cast<const short8*>(sm + psOff + lm * 144 + ks * 64 + quad * 16);
#pragma unroll
      for (int dt = 0; dt < 4; ++dt) {
        int dim = dt * 16 + lm;
        int ph = (ks * 4 + quad + dim) & 7;
        short8 bv = *reinterpret_cast<const short8*>(sm + 8192 + dim * 128 + ph * 16);
        accO[dt] = MFMA16(ap, bv, accO[dt]);
      }
    }
  }
#pragma unroll
  for (int r = 0; r < 4; ++r) {
    float l = lsum[r];
    l += __shfl_xor(l, 1); l += __shfl_xor(l, 2);
    l += __shfl_xor(l, 4); l += __shfl_xor(l, 8);
    lsum[r] = 1.f / l;
  }
  // transpose O through the Ps region for coalesced stores
#pragma unroll
  for (int dt = 0; dt < 4; ++dt)
#pragma unroll
    for (int r = 0; r < 4; ++r)
      *reinterpret_cast<short*>(sm + psOff + (quad * 4 + r) * 144 + (dt * 16 + lm) * 2) =
          bf16s(accO[dt][r] * lsum[r]);
  __builtin_amdgcn_s_waitcnt(0);
  int q2 = lane >> 2, c = lane & 3;
  int tok2 = sortq[sbase + n * 512 + qt * 64 + w * 16 + q2];
  __hip_bfloat16* op = ao + ((size_t)(b * 4096 + tok2) * 16 + h) * 64;
  short8 o0 = *reinterpret_cast<const short8*>(sm + psOff + q2 * 144 + c * 16);
  short8 o1 = *reinterpret_cast<const short8*>(sm + psOff + q2 * 144 + (c + 4) * 16);
  *reinterpret_cast<short8*>(op + c * 8) = o0;
  *reinterpret_cast<short8*>(op + (c + 4) * 8) = o1;
}

// ---------------------------------------------------------------------------
// loss_kernel: extra_loss = (sum_q + sum_k)/16 over (cnt/L)*(psum/L)
// ---------------------------------------------------------------------------
__global__ __launch_bounds__(1024) void loss_kernel(const int* __restrict__ cntg,
                                                    const float* __restrict__ psumg,
                                                    float* __restrict__ out) {
  int t = threadIdx.x;
  float term = ((float)cntg[t] * (1.f / 4096.f)) * (psumg[t] * (1.f / 4096.f));
#pragma unroll
  for (int o = 1; o < 64; o <<= 1) term += __shfl_xor(term, o);
  __shared__ float wsum[16];
  if ((t & 63) == 0) wsum[t >> 6] = term;
  __syncthreads();
  if (t == 0) {
    float s = 0.f;
    for (int i = 0; i < 16; ++i) s += wsum[i];
    out[16777216] = s * (1.f / 16.f);
  }
}

// ---------------------------------------------------------------------------
extern "C" void kernel_launch(void* const* d_in, const int* in_sizes, int n_in,
                              void* d_out, int out_size, void* d_ws, size_t ws_size,
                              hipStream_t stream) {
  (void)in_sizes; (void)n_in; (void)out_size; (void)ws_size;
  const float* x   = (const float*)d_in[0];
  const float* wq  = (const float*)d_in[1];
  const float* bq  = (const float*)d_in[2];
  const float* wk  = (const float*)d_in[3];
  const float* bk  = (const float*)d_in[4];
  const float* wv  = (const float*)d_in[5];
  const float* bv  = (const float*)d_in[6];
  const float* wsh = (const float*)d_in[7];
  const float* wqs = (const float*)d_in[8];
  const float* wks = (const float*)d_in[9];
  const float* wo  = (const float*)d_in[10];
  const float* bo  = (const float*)d_in[11];

  char* ws = (char*)d_ws;
  __hip_bfloat16* wt_qkv = (__hip_bfloat16*)(ws + 0);            // 6291456
  __hip_bfloat16* wt_o   = (__hip_bfloat16*)(ws + 6291456);      // 2097152
  double* wscg  = (double*)(ws + 8388608);                       // 2097152
  double* bsc   = (double*)(ws + 10485760);                      // 2048
  __hip_bfloat16* qkv  = (__hip_bfloat16*)(ws + 10487808);       // 3*33554432 -> ends 111151104
  // overlaid inside qkv region (dead before gemm_k<true> writes qkv):
  __hip_bfloat16* whb = (__hip_bfloat16*)(ws + 109051904);       // 524288
  __hip_bfloat16* wmb = (__hip_bfloat16*)(ws + 109576192);       // 524288
  int* flagcnt = (int*)(ws + 110100480);                         // 256
  int* list    = (int*)(ws + 110100736);                         // 524288
  __hip_bfloat16* attn = (__hip_bfloat16*)(ws + 111151104);      // 33554432
  float* S2 = (float*)(ws + 111151104);  // 16.8MB, overlays attn (dead before attn write)
  int* bid    = (int*)(ws + 144705536);                          // 2097152
  int* sortq  = (int*)(ws + 146802688);                          // 1048576
  int* sortk  = (int*)(ws + 147851264);                          // 1048576
  float* psumg = (float*)(ws + 148899840);                       // 4096
  int* cntg    = (int*)(ws + 148903936);                         // 4096
  __hip_bfloat16* vT = (__hip_bfloat16*)d_out;  // 33.5MB scratch inside out buf
  float* out = (float*)d_out;

  hipMemsetAsync(psumg, 0, 8192, stream);
  hipMemsetAsync(flagcnt, 0, 4, stream);
  prep_wt<<<1024, 256, 0, stream>>>(wq, wk, wv, wo, wt_qkv, wt_o);
  prep_wsc<<<256, 256, 0, stream>>>(wq, wk, wsh, wqs, wks, bq, bk, wscg, bsc, whb, wmb);
  score_gemm<<<dim3(256, 2), 256, 0, stream>>>(x, whb, wmb, bsc, S2);
  bucket_kernel<<<256, 512, 0, stream>>>(S2, bid, psumg, flagcnt, list);
  refine_kernel<<<256, 256, 0, stream>>>(x, wscg, bsc, flagcnt, list, bid);
  sort_kernel<<<128, 256, 0, stream>>>(bid, sortq, sortk, cntg);
  gemm_k<true><<<dim3(128, 24), 256, 0, stream>>>(x, wt_qkv, qkv, bq, bk, bv);
  vt_kernel<<<512, 256, 0, stream>>>(qkv + (size_t)2 * BL * 1024, sortk, vT);
  attn_kernel<<<4096, 256, 0, stream>>>(qkv, qkv + (size_t)BL * 1024, vT, sortq, sortk, attn);
  gemm_k<false><<<dim3(128, 8), 256, 0, stream>>>(attn, wt_o, (void*)out, bo, bo, bo);
  loss_kernel<<<1, 1024, 0, stream>>>(cntg, psumg, out);
}

// Round 5
// 576.846 us; speedup vs baseline: 2.5591x; 1.0577x over previous
//
#include <hip/hip_runtime.h>
#include <hip/hip_bf16.h>

// dims
#define BB 4
#define LL 4096
#define DM 1024
#define HH 16
#define DHD 64
#define KB 8
#define BL 16384  // BB*LL
#define FLAGCAP 131072

typedef __attribute__((ext_vector_type(8))) short short8;
typedef __attribute__((ext_vector_type(4))) short short4v;
typedef __attribute__((ext_vector_type(4))) float float4v;

#define MFMA16(A, Bx, C) __builtin_amdgcn_mfma_f32_16x16x32_bf16(A, Bx, C, 0, 0, 0)

static __device__ __forceinline__ short bf16s(float f) {
  __hip_bfloat16 h = __float2bfloat16(f);
  return *reinterpret_cast<short*>(&h);
}
static __device__ __forceinline__ float b2f(short s) {
  __hip_bfloat16 h = *reinterpret_cast<__hip_bfloat16*>(&s);
  return __bfloat162float(h);
}
// async global->LDS DMA, 16B/lane; LDS dest = uniform base + lane*16
static __device__ __forceinline__ void gl16(const void* g, void* l) {
  __builtin_amdgcn_global_load_lds(
      (const __attribute__((address_space(1))) void*)g,
      (__attribute__((address_space(3))) void*)l, 16, 0, 0);
}

// ---------------------------------------------------------------------------
// xcvt: x fp32 -> xb bf16 (A operand for QKV gemm). grid 8192 x 256.
// ---------------------------------------------------------------------------
__global__ __launch_bounds__(256) void xcvt(const float* __restrict__ x,
                                            __hip_bfloat16* __restrict__ xb) {
  int i = (blockIdx.x * 256 + threadIdx.x) * 8;
  float4 f0 = *reinterpret_cast<const float4*>(x + i);
  float4 f1 = *reinterpret_cast<const float4*>(x + i + 4);
  short8 o;
  o[0] = bf16s(f0.x); o[1] = bf16s(f0.y); o[2] = bf16s(f0.z); o[3] = bf16s(f0.w);
  o[4] = bf16s(f1.x); o[5] = bf16s(f1.y); o[6] = bf16s(f1.z); o[7] = bf16s(f1.w);
  *reinterpret_cast<short8*>(xb + i) = o;
}

// ---------------------------------------------------------------------------
// prep_wt: transpose wq/wk/wv/wo ([k][n] fp32) -> [n][k] bf16
// ---------------------------------------------------------------------------
__global__ __launch_bounds__(256) void prep_wt(const float* __restrict__ wq,
                                               const float* __restrict__ wk,
                                               const float* __restrict__ wv,
                                               const float* __restrict__ wo,
                                               __hip_bfloat16* __restrict__ wt_qkv,
                                               __hip_bfloat16* __restrict__ wt_o) {
  int blk = blockIdx.x;
  int s = blk >> 8;
  int rem = blk & 255;
  int k0 = (rem >> 4) * 64;
  int n0 = (rem & 15) * 64;
  const float* src = (s == 0) ? wq : (s == 1) ? wk : (s == 2) ? wv : wo;
  __hip_bfloat16* dst = (s < 3) ? (wt_qkv + (size_t)s * 1024 * 1024) : wt_o;
  __shared__ float ls[64][65];
  int t = threadIdx.x;
#pragma unroll
  for (int p = 0; p < 4; ++p) {
    int sid = p * 256 + t;
    int r = sid >> 4, c4 = sid & 15;
    float4 v = *reinterpret_cast<const float4*>(src + (size_t)(k0 + r) * 1024 + n0 + c4 * 4);
    ls[r][c4 * 4 + 0] = v.x; ls[r][c4 * 4 + 1] = v.y;
    ls[r][c4 * 4 + 2] = v.z; ls[r][c4 * 4 + 3] = v.w;
  }
  __syncthreads();
#pragma unroll
  for (int p = 0; p < 4; ++p) {
    int sid = p * 256 + t;
    int n = sid >> 4, kq = sid & 15;
    short4v pk;
#pragma unroll
    for (int j = 0; j < 4; ++j) pk[j] = bf16s(ls[kq * 4 + j][n]);
    *reinterpret_cast<short4v*>(dst + (size_t)(n0 + n) * 1024 + k0 + kq * 4) = pk;
  }
}

// ---------------------------------------------------------------------------
// prep_wsc: fused score weights. wscg[g][d][kk] fp64, bsc[col] fp64,
// whb/wmb [col][d] bf16 hi/mid split. grid 256, 256 thr.
// ---------------------------------------------------------------------------
__global__ __launch_bounds__(256) void prep_wsc(const float* __restrict__ wq,
                                                const float* __restrict__ wk,
                                                const float* __restrict__ wsh,
                                                const float* __restrict__ wqs,
                                                const float* __restrict__ wks,
                                                const float* __restrict__ bq,
                                                const float* __restrict__ bk,
                                                double* __restrict__ wscg,
                                                double* __restrict__ bsc,
                                                __hip_bfloat16* __restrict__ whb,
                                                __hip_bfloat16* __restrict__ wmb) {
  int col = blockIdx.x;
  int side = col >> 7, h = (col >> 3) & 15, kk = col & 7;
  int g = side * 16 + h;
  const float* w = side ? wk : wq;
  const float* wscore = side ? wks : wqs;
  __shared__ double mix[64];
  int t = threadIdx.x;
  if (t < 64)
    mix[t] = 0.9 * (double)wsh[(h * 64 + t) * 8 + kk] +
             0.1 * (double)wscore[(h * 64 + t) * 8 + kk];
  __syncthreads();
#pragma unroll
  for (int p = 0; p < 4; ++p) {
    int d = p * 256 + t;
    double acc = 0.0;
    const float* wr = w + (size_t)d * 1024 + h * 64;
#pragma unroll
    for (int j = 0; j < 64; ++j) acc += (double)wr[j] * mix[j];
    wscg[((size_t)g * 1024 + d) * 8 + kk] = acc;
    short hi = bf16s((float)acc);
    short mid = bf16s((float)(acc - (double)b2f(hi)));
    *reinterpret_cast<short*>(whb + (size_t)col * 1024 + d) = hi;
    *reinterpret_cast<short*>(wmb + (size_t)col * 1024 + d) = mid;
  }
  if (t == 0) {
    const float* br = (side ? bk : bq) + h * 64;
    double acc = 0.0;
    for (int j = 0; j < 64; ++j) acc += (double)br[j] * mix[j];
    bsc[col] = acc;
  }
}

// ---------------------------------------------------------------------------
// score_gemm: S = x*Wsc + b via bf16-split MFMA (xh*wh + xh*wm + xl*wh).
// B tiles staged by global_load_lds (swizzle on global source side).
// Tile 64x128, BK=64, grid (256,2), 256 thr. S2[g][t][kk].
// ---------------------------------------------------------------------------
__global__ __launch_bounds__(256) void score_gemm(const float* __restrict__ x,
                                                  const __hip_bfloat16* __restrict__ whb,
                                                  const __hip_bfloat16* __restrict__ wmb,
                                                  const double* __restrict__ bsc,
                                                  float* __restrict__ S2) {
  __shared__ char sm[49152];  // xh 8K | xl 8K | wh 16K | wm 16K
  int t = threadIdx.x;
  int m0 = blockIdx.x * 64;
  int n0 = blockIdx.y * 128;
  int lane = t & 63;
  int wu = __builtin_amdgcn_readfirstlane(t >> 6);
  int lm = lane & 15, quad = lane >> 4;
  int wmr = (wu & 1) * 32, wn = (wu >> 1) * 64;
  int rb = wu * 32, rr = lane >> 3, phys = lane & 7;
  float4v zero = {0.f, 0.f, 0.f, 0.f};
  float4v acc[2][4];
#pragma unroll
  for (int i = 0; i < 2; ++i)
#pragma unroll
    for (int j = 0; j < 4; ++j) acc[i][j] = zero;

  for (int k0 = 0; k0 < 1024; k0 += 64) {
    __syncthreads();
#pragma unroll
    for (int p = 0; p < 2; ++p) {  // A: hi/lo split via VALU
      int sid = p * 256 + t;
      int m = sid >> 3, kc = sid & 7;
      const float* ap = x + (size_t)(m0 + m) * 1024 + k0 + kc * 8;
      float4 f0 = *reinterpret_cast<const float4*>(ap);
      float4 f1 = *reinterpret_cast<const float4*>(ap + 4);
      float vv[8] = {f0.x, f0.y, f0.z, f0.w, f1.x, f1.y, f1.z, f1.w};
      short8 hi, lo;
#pragma unroll
      for (int e = 0; e < 8; ++e) {
        short h = bf16s(vv[e]);
        hi[e] = h;
        lo[e] = bf16s(vv[e] - b2f(h));
      }
      *reinterpret_cast<short8*>(sm + m * 128 + ((kc + m) & 7) * 16) = hi;
      *reinterpret_cast<short8*>(sm + 8192 + m * 128 + ((kc + m) & 7) * 16) = lo;
    }
#pragma unroll
    for (int p = 0; p < 4; ++p) {  // B: async DMA, swizzled global source
      int row = rb + p * 8 + rr;
      int kc = (phys - row) & 7;
      gl16(whb + (size_t)(n0 + row) * 1024 + k0 + kc * 8, sm + 16384 + (rb + p * 8) * 128);
      gl16(wmb + (size_t)(n0 + row) * 1024 + k0 + kc * 8, sm + 32768 + (rb + p * 8) * 128);
    }
    __syncthreads();
#pragma unroll
    for (int kh = 0; kh < 2; ++kh) {
      short8 ah[2], al[2], bh[4], bm[4];
#pragma unroll
      for (int i = 0; i < 2; ++i) {
        int row = wmr + i * 16 + lm;
        int ph = ((kh * 4 + quad) + row) & 7;
        ah[i] = *reinterpret_cast<const short8*>(sm + row * 128 + ph * 16);
        al[i] = *reinterpret_cast<const short8*>(sm + 8192 + row * 128 + ph * 16);
      }
#pragma unroll
      for (int j = 0; j < 4; ++j) {
        int rn = wn + j * 16 + lm;
        int ph = ((kh * 4 + quad) + rn) & 7;
        bh[j] = *reinterpret_cast<const short8*>(sm + 16384 + rn * 128 + ph * 16);
        bm[j] = *reinterpret_cast<const short8*>(sm + 32768 + rn * 128 + ph * 16);
      }
#pragma unroll
      for (int i = 0; i < 2; ++i)
#pragma unroll
        for (int j = 0; j < 4; ++j) {
          acc[i][j] = MFMA16(ah[i], bh[j], acc[i][j]);
          acc[i][j] = MFMA16(ah[i], bm[j], acc[i][j]);
          acc[i][j] = MFMA16(al[i], bh[j], acc[i][j]);
        }
    }
  }

#pragma unroll
  for (int i = 0; i < 2; ++i)
#pragma unroll
    for (int j = 0; j < 4; ++j) {
      int n = n0 + wn + j * 16 + lm;
      float bias = (float)bsc[n];
#pragma unroll
      for (int r = 0; r < 4; ++r) {
        int row = m0 + wmr + i * 16 + quad * 4 + r;
        S2[(size_t)(n >> 3) * 131072 + row * 8 + (n & 7)] = acc[i][j][r] + bias;
      }
    }
}

// ---------------------------------------------------------------------------
// bucket_kernel: argmax -> bid, softmax prob sums -> psumg, flag near-ties.
// ---------------------------------------------------------------------------
__global__ __launch_bounds__(512) void bucket_kernel(const float* __restrict__ S2,
                                                     int* __restrict__ bid,
                                                     float* __restrict__ psumg,
                                                     int* __restrict__ flagcnt,
                                                     int* __restrict__ list) {
  int t = threadIdx.x;
  int lane = t & 63;
  int w = t >> 6;
  int T0 = blockIdx.x * 64;
  int tg = T0 + lane;
  int b = tg >> 12, l = tg & 4095;
#pragma unroll
  for (int gi = 0; gi < 4; ++gi) {
    int g = gi * 8 + w;
    const float* sp = S2 + (size_t)g * 131072 + tg * 8;
    float4 v0 = *reinterpret_cast<const float4*>(sp);
    float4 v1 = *reinterpret_cast<const float4*>(sp + 4);
    float v[8] = {v0.x, v0.y, v0.z, v0.w, v1.x, v1.y, v1.z, v1.w};
    float mx = v[0]; int am = 0;
#pragma unroll
    for (int j = 1; j < 8; ++j) { if (v[j] > mx) { mx = v[j]; am = j; } }
    float mx2 = -3.0e38f;
#pragma unroll
    for (int j = 0; j < 8; ++j) { if (j != am && v[j] > mx2) mx2 = v[j]; }
    int side = g >> 4, h = g & 15;
    int slab = (side * 4 + b) * 16 + h;
    bid[(slab << 12) | l] = am;
    if (mx - mx2 < 5e-4f) {
      int pos = atomicAdd(flagcnt, 1);
      if (pos < FLAGCAP) list[pos] = (slab << 12) | l;
    }
    float es = 0.f, e[8];
#pragma unroll
    for (int j = 0; j < 8; ++j) { e[j] = __expf(v[j] - mx); es += e[j]; }
    float inv = 1.f / es;
#pragma unroll
    for (int j = 0; j < 8; ++j) {
      float s = e[j] * inv;
      s += __shfl_xor(s, 1);  s += __shfl_xor(s, 2);  s += __shfl_xor(s, 4);
      s += __shfl_xor(s, 8);  s += __shfl_xor(s, 16); s += __shfl_xor(s, 32);
      if (lane == 0) atomicAdd(&psumg[slab * 8 + j], s);
    }
  }
}

// ---------------------------------------------------------------------------
// refine_kernel: exact fp64 scores for flagged tokens; overwrite bid.
// ---------------------------------------------------------------------------
__global__ __launch_bounds__(256) void refine_kernel(const float* __restrict__ x,
                                                     const double* __restrict__ wscg,
                                                     const double* __restrict__ bsc,
                                                     const int* __restrict__ flagcnt,
                                                     const int* __restrict__ list,
                                                     int* __restrict__ bid) {
  int lane = threadIdx.x & 63;
  int w = threadIdx.x >> 6;
  int cnt = flagcnt[0];
  if (cnt > FLAGCAP) cnt = FLAGCAP;
  for (int i = blockIdx.x * 4 + w; i < cnt; i += 1024) {
    int e = list[i];
    int slab = e >> 12, l = e & 4095;
    int side = slab >> 6, b = (slab >> 4) & 3, h = slab & 15;
    int g = side * 16 + h;
    int row = b * 4096 + l;
    double acc[8] = {0, 0, 0, 0, 0, 0, 0, 0};
    const float* xr = x + (size_t)row * 1024 + lane * 16;
    const double* wr = wscg + ((size_t)g * 1024 + lane * 16) * 8;
#pragma unroll
    for (int dd = 0; dd < 16; ++dd) {
      double xv = (double)xr[dd];
#pragma unroll
      for (int j = 0; j < 8; ++j) acc[j] += xv * wr[dd * 8 + j];
    }
#pragma unroll
    for (int j = 0; j < 8; ++j) {
      double v = acc[j];
      v += __shfl_xor(v, 32); v += __shfl_xor(v, 16); v += __shfl_xor(v, 8);
      v += __shfl_xor(v, 4);  v += __shfl_xor(v, 2);  v += __shfl_xor(v, 1);
      acc[j] = v + bsc[g * 8 + j];
    }
    if (lane == 0) {
      double mx = acc[0]; int am = 0;
#pragma unroll
      for (int j = 1; j < 8; ++j) { if (acc[j] > mx) { mx = acc[j]; am = j; } }
      bid[(slab << 12) | l] = am;
    }
  }
}

// ---------------------------------------------------------------------------
// sort_kernel: stable counting sort into 8 buckets per (side,b,h)
// ---------------------------------------------------------------------------
__global__ __launch_bounds__(256) void sort_kernel(const int* __restrict__ bid,
                                                   int* __restrict__ sortq,
                                                   int* __restrict__ sortk,
                                                   int* __restrict__ cntg) {
  int blk = blockIdx.x;
  int side = blk >> 6, b = (blk >> 4) & 3, h = blk & 15;
  const int* ids = bid + (((side * 4 + b) * 16 + h) << 12);
  int* outp = (side ? sortk : sortq) + ((b * 16 + h) << 12);
  __shared__ int cnt[8][257];
  __shared__ int base[8];
  int t = threadIdx.x;
  int loc[16];
  int hist[8] = {0, 0, 0, 0, 0, 0, 0, 0};
#pragma unroll
  for (int j = 0; j < 16; ++j) { loc[j] = ids[t * 16 + j] & 7; hist[loc[j]]++; }
#pragma unroll
  for (int k = 0; k < 8; ++k) cnt[k][t + 1] = hist[k];
  if (t < 8) cnt[t][0] = 0;
  __syncthreads();
  if (t < 8) {
    for (int i = 1; i <= 256; ++i) cnt[t][i] += cnt[t][i - 1];
  }
  __syncthreads();
  if (t == 0) {
    int run = 0;
    for (int k = 0; k < 8; ++k) { base[k] = run; run += cnt[k][256]; }
  }
  if (t < 8) cntg[((side * 4 + b) * 16 + h) * 8 + t] = cnt[t][256];
  __syncthreads();
#pragma unroll
  for (int j = 0; j < 16; ++j) {
    int k = loc[j];
    int before = 0;
#pragma unroll
    for (int i = 0; i < 16; ++i) before += (i < j && loc[i] == k) ? 1 : 0;
    int pos = base[k] + cnt[k][t] + before;
    outp[pos] = t * 16 + j;
  }
}

// ---------------------------------------------------------------------------
// gemm_k: C[M,N] = A[M,1024](bf16) * Bt[N,1024]^T (+bias). 128x128, BK=64.
// Staging via global_load_lds (swizzle on global source). Flat grid, m-major
// (blocks sharing an A-panel co-resident -> A fetched ~once).
// CBF16: C bf16 (QKV, 3 biases by n>>10) else C fp32 (out-proj).
// ---------------------------------------------------------------------------
template <bool CBF16>
__global__ __launch_bounds__(256) void gemm_k(const __hip_bfloat16* __restrict__ A,
                                              const __hip_bfloat16* __restrict__ Bt,
                                              void* __restrict__ Cv,
                                              const float* __restrict__ b0,
                                              const float* __restrict__ b1,
                                              const float* __restrict__ b2,
                                              int nblk) {
  __shared__ char sm[32768];
  int t = threadIdx.x;
  int blk = blockIdx.x;
  int m0 = (blk / nblk) * 128;
  int n0 = (blk % nblk) * 128;
  int lane = t & 63;
  int wu = __builtin_amdgcn_readfirstlane(t >> 6);
  int lm = lane & 15, quad = lane >> 4;
  int wm = (wu & 1) * 64, wn = (wu >> 1) * 64;
  int rb = wu * 32, rr = lane >> 3, phys = lane & 7;
  float4v zero = {0.f, 0.f, 0.f, 0.f};
  float4v acc[4][4];
#pragma unroll
  for (int i = 0; i < 4; ++i)
#pragma unroll
    for (int j = 0; j < 4; ++j) acc[i][j] = zero;

  for (int k0 = 0; k0 < 1024; k0 += 64) {
    __syncthreads();
#pragma unroll
    for (int p = 0; p < 4; ++p) {
      int row = rb + p * 8 + rr;
      int kc = (phys - row) & 7;  // global-side swizzle -> LDS [row][(kc+row)&7]
      gl16(A + (size_t)(m0 + row) * 1024 + k0 + kc * 8, sm + (rb + p * 8) * 128);
      gl16(Bt + (size_t)(n0 + row) * 1024 + k0 + kc * 8, sm + 16384 + (rb + p * 8) * 128);
    }
    __syncthreads();
#pragma unroll
    for (int kh = 0; kh < 2; ++kh) {
      short8 af[4], bf[4];
#pragma unroll
      for (int i = 0; i < 4; ++i) {
        int row = wm + i * 16 + lm;
        int ph = ((kh * 4 + quad) + row) & 7;
        af[i] = *reinterpret_cast<const short8*>(sm + row * 128 + ph * 16);
        int rn = wn + i * 16 + lm;
        int phb = ((kh * 4 + quad) + rn) & 7;
        bf[i] = *reinterpret_cast<const short8*>(sm + 16384 + rn * 128 + phb * 16);
      }
#pragma unroll
      for (int i = 0; i < 4; ++i)
#pragma unroll
        for (int j = 0; j < 4; ++j) acc[i][j] = MFMA16(af[i], bf[j], acc[i][j]);
    }
  }

  if constexpr (CBF16) {
    int s = n0 >> 10, nnb = n0 & 1023;
    const float* bias = (s == 0) ? b0 : (s == 1) ? b1 : b2;
    __hip_bfloat16* C = (__hip_bfloat16*)Cv + (size_t)s * BL * 1024;
#pragma unroll
    for (int i = 0; i < 4; ++i)
#pragma unroll
      for (int j = 0; j < 4; ++j) {
        int nn = nnb + wn + j * 16 + lm;
        float bvx = bias[nn];
#pragma unroll
        for (int r = 0; r < 4; ++r) {
          int row = m0 + wm + i * 16 + quad * 4 + r;
          C[(size_t)row * 1024 + nn] = __float2bfloat16(acc[i][j][r] + bvx);
        }
      }
  } else {
    float* C = (float*)Cv;
#pragma unroll
    for (int i = 0; i < 4; ++i)
#pragma unroll
      for (int j = 0; j < 4; ++j) {
        int gn = n0 + wn + j * 16 + lm;
        float bvx = b0[gn];
#pragma unroll
        for (int r = 0; r < 4; ++r) {
          int row = m0 + wm + i * 16 + quad * 4 + r;
          C[(size_t)row * 1024 + gn] = acc[i][j][r] + bvx;
        }
      }
  }
}

// ---------------------------------------------------------------------------
// vt_kernel: gather sorted V and transpose -> vT[cid][dim][key]
// ---------------------------------------------------------------------------
__global__ __launch_bounds__(256) void vt_kernel(const __hip_bfloat16* __restrict__ vb,
                                                 const int* __restrict__ sortk,
                                                 __hip_bfloat16* __restrict__ vT) {
  int cid = blockIdx.x;
  int b = cid >> 7, h = (cid >> 3) & 15, n = cid & 7;
  int sbase = ((b * 16 + h) << 12) + n * 512;
  __shared__ __hip_bfloat16 ls[64][72];
  int t = threadIdx.x;
  for (int kt = 0; kt < 8; ++kt) {
    __syncthreads();
#pragma unroll
    for (int p = 0; p < 2; ++p) {
      int sid = p * 256 + t;
      int key = sid >> 3, kc = sid & 7;
      int tok = sortk[sbase + kt * 64 + key];
      short8 v = *reinterpret_cast<const short8*>(vb + ((size_t)(b * 4096 + tok) * 16 + h) * 64 + kc * 8);
      *reinterpret_cast<short8*>(&ls[key][kc * 8]) = v;
    }
    __syncthreads();
#pragma unroll
    for (int p = 0; p < 2; ++p) {
      int sid = p * 256 + t;
      int dim = sid >> 3, kc = sid & 7;
      short8 o;
#pragma unroll
      for (int j = 0; j < 8; ++j) o[j] = *reinterpret_cast<short*>(&ls[kc * 8 + j][dim]);
      *reinterpret_cast<short8*>(vT + ((size_t)cid * 64 + dim) * 512 + kt * 64 + kc * 8) = o;
    }
  }
}

// ---------------------------------------------------------------------------
// attn_kernel: per (chunk, 64-query tile). Wave = 16 queries. K-tiles of 64.
// ---------------------------------------------------------------------------
__global__ __launch_bounds__(256) void attn_kernel(const __hip_bfloat16* __restrict__ qb,
                                                   const __hip_bfloat16* __restrict__ kb,
                                                   const __hip_bfloat16* __restrict__ vT,
                                                   const int* __restrict__ sortq,
                                                   const int* __restrict__ sortk,
                                                   __hip_bfloat16* __restrict__ ao) {
  __shared__ char sm[25600];  // Ks 8K | Vs 8K | Ps 4 waves x 16 x 144B
  int t = threadIdx.x;
  int lane = t & 63, w = t >> 6;
  int lm = lane & 15, quad = lane >> 4;
  int cid = blockIdx.x >> 3, qt = blockIdx.x & 7;
  int b = cid >> 7, h = (cid >> 3) & 15, n = cid & 7;
  int sbase = (b * 16 + h) << 12;
  int psOff = 16384 + w * 2304;

  int qtok = sortq[sbase + n * 512 + qt * 64 + w * 16 + lm];
  const __hip_bfloat16* qp = qb + ((size_t)(b * 4096 + qtok) * 16 + h) * 64 + quad * 8;
  short8 aq0 = *reinterpret_cast<const short8*>(qp);
  short8 aq1 = *reinterpret_cast<const short8*>(qp + 32);

  float4v zero = {0.f, 0.f, 0.f, 0.f};
  float4v accO[4];
#pragma unroll
  for (int i = 0; i < 4; ++i) accO[i] = zero;
  float lsum[4] = {0.f, 0.f, 0.f, 0.f};

  for (int kt = 0; kt < 8; ++kt) {
    __syncthreads();
#pragma unroll
    for (int p = 0; p < 2; ++p) {
      int sid = p * 256 + t;
      int row = sid >> 3, kc = sid & 7;
      int tok = sortk[sbase + n * 512 + kt * 64 + row];
      short8 kv = *reinterpret_cast<const short8*>(kb + ((size_t)(b * 4096 + tok) * 16 + h) * 64 + kc * 8);
      *reinterpret_cast<short8*>(sm + row * 128 + ((kc + row) & 7) * 16) = kv;
      short8 vv = *reinterpret_cast<const short8*>(vT + ((size_t)cid * 64 + row) * 512 + kt * 64 + kc * 8);
      *reinterpret_cast<short8*>(sm + 8192 + row * 128 + ((kc + row) & 7) * 16) = vv;
    }
    __syncthreads();
#pragma unroll
    for (int nt = 0; nt < 4; ++nt) {
      int key = nt * 16 + lm;
      int ph0 = (quad + key) & 7;
      int ph1 = (4 + quad + key) & 7;
      short8 bk0 = *reinterpret_cast<const short8*>(sm + key * 128 + ph0 * 16);
      short8 bk1 = *reinterpret_cast<const short8*>(sm + key * 128 + ph1 * 16);
      float4v S = zero;
      S = MFMA16(aq0, bk0, S);
      S = MFMA16(aq1, bk1, S);
#pragma unroll
      for (int r = 0; r < 4; ++r) {
        float e = __expf(S[r] * 0.125f);
        lsum[r] += e;
        *reinterpret_cast<short*>(sm + psOff + (quad * 4 + r) * 144 + key * 2) = bf16s(e);
      }
    }
    __builtin_amdgcn_s_waitcnt(0);  // P writes visible before P reads (same wave)
#pragma unroll
    for (int ks = 0; ks < 2; ++ks) {
      short8 ap = *reinterpret_cast<const short8*>(sm + psOff + lm * 144 + ks * 64 + quad * 16);
#pragma unroll
      for (int dt = 0; dt < 4; ++dt) {
        int dim = dt * 16 + lm;
        int ph = (ks * 4 + quad + dim) & 7;
        short8 bv = *reinterpret_cast<const short8*>(sm + 8192 + dim * 128 + ph * 16);
        accO[dt] = MFMA16(ap, bv, accO[dt]);
      }
    }
  }
#pragma unroll
  for (int r = 0; r < 4; ++r) {
    float l = lsum[r];
    l += __shfl_xor(l, 1); l += __shfl_xor(l, 2);
    l += __shfl_xor(l, 4); l += __shfl_xor(l, 8);
    lsum[r] = 1.f / l;
  }
  // transpose O through the Ps region for coalesced stores
#pragma unroll
  for (int dt = 0; dt < 4; ++dt)
#pragma unroll
    for (int r = 0; r < 4; ++r)
      *reinterpret_cast<short*>(sm + psOff + (quad * 4 + r) * 144 + (dt * 16 + lm) * 2) =
          bf16s(accO[dt][r] * lsum[r]);
  __builtin_amdgcn_s_waitcnt(0);
  int q2 = lane >> 2, c = lane & 3;
  int tok2 = sortq[sbase + n * 512 + qt * 64 + w * 16 + q2];
  __hip_bfloat16* op = ao + ((size_t)(b * 4096 + tok2) * 16 + h) * 64;
  short8 o0 = *reinterpret_cast<const short8*>(sm + psOff + q2 * 144 + c * 16);
  short8 o1 = *reinterpret_cast<const short8*>(sm + psOff + q2 * 144 + (c + 4) * 16);
  *reinterpret_cast<short8*>(op + c * 8) = o0;
  *reinterpret_cast<short8*>(op + (c + 4) * 8) = o1;
}

// ---------------------------------------------------------------------------
// loss_kernel: extra_loss = (sum_q + sum_k)/16 over (cnt/L)*(psum/L)
// ---------------------------------------------------------------------------
__global__ __launch_bounds__(1024) void loss_kernel(const int* __restrict__ cntg,
                                                    const float* __restrict__ psumg,
                                                    float* __restrict__ out) {
  int t = threadIdx.x;
  float term = ((float)cntg[t] * (1.f / 4096.f)) * (psumg[t] * (1.f / 4096.f));
#pragma unroll
  for (int o = 1; o < 64; o <<= 1) term += __shfl_xor(term, o);
  __shared__ float wsum[16];
  if ((t & 63) == 0) wsum[t >> 6] = term;
  __syncthreads();
  if (t == 0) {
    float s = 0.f;
    for (int i = 0; i < 16; ++i) s += wsum[i];
    out[16777216] = s * (1.f / 16.f);
  }
}

// ---------------------------------------------------------------------------
extern "C" void kernel_launch(void* const* d_in, const int* in_sizes, int n_in,
                              void* d_out, int out_size, void* d_ws, size_t ws_size,
                              hipStream_t stream) {
  (void)in_sizes; (void)n_in; (void)out_size; (void)ws_size;
  const float* x   = (const float*)d_in[0];
  const float* wq  = (const float*)d_in[1];
  const float* bq  = (const float*)d_in[2];
  const float* wk  = (const float*)d_in[3];
  const float* bk  = (const float*)d_in[4];
  const float* wv  = (const float*)d_in[5];
  const float* bv  = (const float*)d_in[6];
  const float* wsh = (const float*)d_in[7];
  const float* wqs = (const float*)d_in[8];
  const float* wks = (const float*)d_in[9];
  const float* wo  = (const float*)d_in[10];
  const float* bo  = (const float*)d_in[11];

  char* ws = (char*)d_ws;
  __hip_bfloat16* wt_qkv = (__hip_bfloat16*)(ws + 0);            // 6291456
  __hip_bfloat16* wt_o   = (__hip_bfloat16*)(ws + 6291456);      // 2097152
  double* wscg  = (double*)(ws + 8388608);                       // 2097152
  double* bsc   = (double*)(ws + 10485760);                      // 2048
  __hip_bfloat16* qkv  = (__hip_bfloat16*)(ws + 10487808);       // 3*33554432 -> ends 111151104
  // overlaid inside qkv region (dead before gemm_k<true> writes qkv):
  __hip_bfloat16* whb = (__hip_bfloat16*)(ws + 109051904);       // 524288
  __hip_bfloat16* wmb = (__hip_bfloat16*)(ws + 109576192);       // 524288
  int* flagcnt = (int*)(ws + 110100480);                         // 256
  int* list    = (int*)(ws + 110100736);                         // 524288
  __hip_bfloat16* attn = (__hip_bfloat16*)(ws + 111151104);      // 33554432
  float* S2 = (float*)(ws + 111151104);  // 16.8MB, overlays attn (dead before attn write)
  int* bid    = (int*)(ws + 144705536);                          // 2097152
  int* sortq  = (int*)(ws + 146802688);                          // 1048576
  int* sortk  = (int*)(ws + 147851264);                          // 1048576
  float* psumg = (float*)(ws + 148899840);                       // 4096
  int* cntg    = (int*)(ws + 148903936);                         // 4096
  // d_out (67.1 MB): [0,33.5M) vT scratch; [33.5M,67.1M) xb scratch. Both dead
  // before gemm_k<false> + loss write the real output.
  __hip_bfloat16* vT = (__hip_bfloat16*)d_out;
  __hip_bfloat16* xb = (__hip_bfloat16*)((char*)d_out + 33554432);
  float* out = (float*)d_out;

  hipMemsetAsync(psumg, 0, 8192, stream);
  hipMemsetAsync(flagcnt, 0, 4, stream);
  prep_wt<<<1024, 256, 0, stream>>>(wq, wk, wv, wo, wt_qkv, wt_o);
  prep_wsc<<<256, 256, 0, stream>>>(wq, wk, wsh, wqs, wks, bq, bk, wscg, bsc, whb, wmb);
  xcvt<<<8192, 256, 0, stream>>>(x, xb);
  score_gemm<<<dim3(256, 2), 256, 0, stream>>>(x, whb, wmb, bsc, S2);
  bucket_kernel<<<256, 512, 0, stream>>>(S2, bid, psumg, flagcnt, list);
  refine_kernel<<<256, 256, 0, stream>>>(x, wscg, bsc, flagcnt, list, bid);
  sort_kernel<<<128, 256, 0, stream>>>(bid, sortq, sortk, cntg);
  gemm_k<true><<<3072, 256, 0, stream>>>(xb, wt_qkv, qkv, bq, bk, bv, 24);
  vt_kernel<<<512, 256, 0, stream>>>(qkv + (size_t)2 * BL * 1024, sortk, vT);
  attn_kernel<<<4096, 256, 0, stream>>>(qkv, qkv + (size_t)BL * 1024, vT, sortq, sortk, attn);
  gemm_k<false><<<1024, 256, 0, stream>>>(attn, wt_o, (void*)out, bo, bo, bo, 8);
  loss_kernel<<<1, 1024, 0, stream>>>(cntg, psumg, out);
}